// Round 7
// baseline (744.580 us; speedup 1.0000x reference)
//
#include <hip/hip_runtime.h>
#include <math.h>

#define N_ATOMS 40000
#define E_EDGES 640000
#define H 128
#define RBF 64
#define NBLK 3
#define CUTF 5.0f
#define TBL 4096   // filter lookup table entries per block (2 MB -> L2-resident)

// stable fast tanh: exp-based, saturates correctly at +/-inf
__device__ __forceinline__ float fast_tanh(float x) {
    return 1.0f - 2.0f / (1.0f + __expf(2.0f * x));
}

// ---------------- embW = emb @ lin1[0]  (100 x 128) ----------------
__global__ __launch_bounds__(128) void k_embw(const float* __restrict__ emb,
                                              const float* __restrict__ lin1,
                                              float* __restrict__ embw) {
    const int t = blockIdx.x;
    const int c = threadIdx.x;
    float s = 0.0f;
#pragma unroll 8
    for (int k = 0; k < H; ++k) s = fmaf(emb[t * H + k], lin1[(size_t)k * H + c], s);
    embw[t * H + c] = s;
}

// ---------------- K0: x = emb[atom_types]; h = embW[atom_types] ----------------
__global__ __launch_bounds__(256) void k_embed2(const int* __restrict__ types,
                                                const float* __restrict__ emb,
                                                const float* __restrict__ embw,
                                                float* __restrict__ x,
                                                float* __restrict__ h) {
    int flat4 = blockIdx.x * 256 + threadIdx.x;  // over N*H/4
    int i = flat4 >> 5;
    int c4 = flat4 & 31;
    int t = types[i];
    ((float4*)(x + (size_t)i * H))[c4] = ((const float4*)(emb + (size_t)t * H))[c4];
    ((float4*)(h + (size_t)i * H))[c4] = ((const float4*)(embw + (size_t)t * H))[c4];
}

// ---------------- CSR build ----------------
__global__ __launch_bounds__(256) void k_count(const int* __restrict__ eidx,
                                               int* __restrict__ cnt) {
    int e = blockIdx.x * 256 + threadIdx.x;
    atomicAdd(&cnt[eidx[E_EDGES + e]], 1);
}

__global__ __launch_bounds__(1024) void k_scanA(const int* __restrict__ cnt,
                                                int* __restrict__ bsum) {
    __shared__ int ws[16];
    const int tid = threadIdx.x, lane = tid & 63, wid = tid >> 6;
    int idx = blockIdx.x * 1024 + tid;
    int v = (idx < N_ATOMS) ? cnt[idx] : 0;
#pragma unroll
    for (int off = 32; off; off >>= 1) v += __shfl_xor(v, off, 64);
    if (lane == 0) ws[wid] = v;
    __syncthreads();
    if (tid == 0) {
        int s = 0;
#pragma unroll
        for (int w = 0; w < 16; ++w) s += ws[w];
        bsum[blockIdx.x] = s;
    }
}

__global__ __launch_bounds__(64) void k_scanB(const int* __restrict__ bsum,
                                              int* __restrict__ boff) {
    const int lane = threadIdx.x;
    int v = (lane < 40) ? bsum[lane] : 0;
    int inc = v;
#pragma unroll
    for (int off = 1; off < 64; off <<= 1) {
        int t = __shfl_up(inc, off, 64);
        if (lane >= off) inc += t;
    }
    if (lane < 40) boff[lane] = inc - v;
}

__global__ __launch_bounds__(1024) void k_scanC(const int* __restrict__ cnt,
                                                const int* __restrict__ boff,
                                                int* __restrict__ cursor,
                                                int* __restrict__ rstart) {
    __shared__ int wsum[16];
    __shared__ int woff[16];
    const int tid = threadIdx.x, lane = tid & 63, wid = tid >> 6;
    int idx = blockIdx.x * 1024 + tid;
    int v = (idx < N_ATOMS) ? cnt[idx] : 0;
    int inc = v;
#pragma unroll
    for (int off = 1; off < 64; off <<= 1) {
        int t = __shfl_up(inc, off, 64);
        if (lane >= off) inc += t;
    }
    if (lane == 63) wsum[wid] = inc;
    __syncthreads();
    if (tid == 0) {
        int acc = 0;
#pragma unroll
        for (int w = 0; w < 16; ++w) { woff[w] = acc; acc += wsum[w]; }
    }
    __syncthreads();
    if (idx < N_ATOMS) {
        int ex = boff[blockIdx.x] + woff[wid] + inc - v;
        cursor[idx] = ex;
        rstart[idx] = ex;
    }
}

// fill: pmeta[pos] = {src, float_bits(u)}, u = d*(TBL-1)/CUT (dst-sorted)
__global__ __launch_bounds__(256) void k_fill(const int* __restrict__ eidx,
                                              const float* __restrict__ ew,
                                              int* __restrict__ cursor,
                                              int2* __restrict__ pmeta) {
    int e = blockIdx.x * 256 + threadIdx.x;
    int dd = eidx[E_EDGES + e];
    int pos = atomicAdd(&cursor[dd], 1);
    float u = ew[e] * ((float)(TBL - 1) / CUTF);
    pmeta[pos] = make_int2(eidx[e], __float_as_int(u));
}

// ---------------- K1: filter table build ----------------
__global__ __launch_bounds__(256, 2) void k_table(const float* __restrict__ fw1all,
                                                  const float* __restrict__ fb1all,
                                                  const float* __restrict__ fw2all,
                                                  const float* __restrict__ fb2all,
                                                  float* __restrict__ tab) {
    const int b = blockIdx.y;
    const float* fw1 = fw1all + (size_t)b * RBF * H;
    const float* fb1 = fb1all + (size_t)b * H;
    const float* fw2 = fw2all + (size_t)b * H * H;
    const float* fb2 = fb2all + (size_t)b * H;
    float* tabB = tab + (size_t)b * TBL * H;

    __shared__ float tile[128 * 133];
    const int tid = threadIdx.x;
    const int mbase = blockIdx.x * 128;
    const float DSTEP = CUTF / (float)(TBL - 1);

    {
        const int e = tid & 127;
        const int k0 = (tid >> 7) * 32;
        const float d = (float)(mbase + e) * DSTEP;
        const float DELTA = CUTF / 63.0f;
        const float COEFF = -0.5f / (DELTA * DELTA);
#pragma unroll
        for (int k = k0; k < k0 + 32; ++k) {
            float diff = d - (float)k * DELTA;
            tile[e * 133 + k] = __expf(COEFF * diff * diff);
        }
    }
    __syncthreads();

    const int eg = tid >> 4, cg = tid & 15;
    const int e0 = eg * 8, c0 = cg * 8;

    float acc[8][8];
#pragma unroll
    for (int i = 0; i < 8; ++i)
#pragma unroll
        for (int j = 0; j < 8; ++j) acc[i][j] = 0.0f;

#pragma unroll 4
    for (int k = 0; k < RBF; ++k) {
        float a[8];
#pragma unroll
        for (int i = 0; i < 8; ++i) a[i] = tile[(e0 + i) * 133 + k];
        const float4 b0 = *(const float4*)(fw1 + (size_t)k * H + c0);
        const float4 b1 = *(const float4*)(fw1 + (size_t)k * H + c0 + 4);
        const float bb[8] = {b0.x, b0.y, b0.z, b0.w, b1.x, b1.y, b1.z, b1.w};
#pragma unroll
        for (int i = 0; i < 8; ++i)
#pragma unroll
            for (int j = 0; j < 8; ++j) acc[i][j] = fmaf(a[i], bb[j], acc[i][j]);
    }

    {
        const float4 q0 = *(const float4*)(fb1 + c0);
        const float4 q1 = *(const float4*)(fb1 + c0 + 4);
        const float bv[8] = {q0.x, q0.y, q0.z, q0.w, q1.x, q1.y, q1.z, q1.w};
#pragma unroll
        for (int i = 0; i < 8; ++i)
#pragma unroll
            for (int j = 0; j < 8; ++j) acc[i][j] = fast_tanh(acc[i][j] + bv[j]);
    }

    __syncthreads();
#pragma unroll
    for (int i = 0; i < 8; ++i)
#pragma unroll
        for (int j = 0; j < 8; ++j) tile[(e0 + i) * 133 + c0 + j] = acc[i][j];
    __syncthreads();

#pragma unroll
    for (int i = 0; i < 8; ++i)
#pragma unroll
        for (int j = 0; j < 8; ++j) acc[i][j] = 0.0f;

#pragma unroll 4
    for (int k = 0; k < H; ++k) {
        float a[8];
#pragma unroll
        for (int i = 0; i < 8; ++i) a[i] = tile[(e0 + i) * 133 + k];
        const float4 b0 = *(const float4*)(fw2 + (size_t)k * H + c0);
        const float4 b1 = *(const float4*)(fw2 + (size_t)k * H + c0 + 4);
        const float bb[8] = {b0.x, b0.y, b0.z, b0.w, b1.x, b1.y, b1.z, b1.w};
#pragma unroll
        for (int i = 0; i < 8; ++i)
#pragma unroll
            for (int j = 0; j < 8; ++j) acc[i][j] = fmaf(a[i], bb[j], acc[i][j]);
    }

    const float4 q0 = *(const float4*)(fb2 + c0);
    const float4 q1 = *(const float4*)(fb2 + c0 + 4);
    const float bv[8] = {q0.x, q0.y, q0.z, q0.w, q1.x, q1.y, q1.z, q1.w};

#pragma unroll
    for (int ei = 0; ei < 8; ++ei) {
        const int m = mbase + e0 + ei;
        const float d = (float)m * DSTEP;
        float c = 0.5f * (cosf(0.6283185307179586f * d) + 1.0f);
        c = (d < CUTF) ? c : 0.0f;
        float* op = tabB + (size_t)m * H + c0;
        float r[8];
#pragma unroll
        for (int j = 0; j < 8; ++j) r[j] = (acc[ei][j] + bv[j]) * c;
        *(float4*)(op)     = make_float4(r[0], r[1], r[2], r[3]);
        *(float4*)(op + 4) = make_float4(r[4], r[5], r[6], r[7]);
    }
}

// ---------------- fused tail (256 thr, 32-atom tile, 2x8 micro):
// x += tanh(agg@lin2+b2)@linw + bl ; optionally h = x_new@lin1_next
// 1250 blocks -> ~19 waves/CU of TLP (the round-6 version starved at ~6).
template <bool MAKE_H>
__global__ __launch_bounds__(256) void k_tail(const float* __restrict__ agg,
                                              const float* __restrict__ lin2,
                                              const float* __restrict__ b2,
                                              const float* __restrict__ linw,
                                              const float* __restrict__ bl,
                                              float* __restrict__ x,
                                              const float* __restrict__ lin1n,
                                              float* __restrict__ hout) {
    __shared__ float at[32 * 133];
    const int tid = threadIdx.x;
    const int abase = blockIdx.x * 32;

    // stage agg tile [32][128] -> LDS
#pragma unroll
    for (int i = 0; i < 4; ++i) {
        int flat4 = tid + 256 * i;
        int r = flat4 >> 5, k4 = flat4 & 31;
        float4 v = ((const float4*)(agg + (size_t)(abase + r) * H))[k4];
        float* dp = &at[r * 133 + k4 * 4];
        dp[0] = v.x; dp[1] = v.y; dp[2] = v.z; dp[3] = v.w;
    }
    __syncthreads();

    const int eg = tid >> 4, cg = tid & 15;   // 16 x 16 thread grid
    const int r0 = eg * 2, c0 = cg * 8;       // 2 rows x 8 cols per thread

    float acc[2][8];
#pragma unroll
    for (int i = 0; i < 2; ++i)
#pragma unroll
        for (int j = 0; j < 8; ++j) acc[i][j] = 0.0f;

    // stage 1: agg @ lin2, tanh
#pragma unroll 4
    for (int k = 0; k < H; ++k) {
        float a[2];
#pragma unroll
        for (int i = 0; i < 2; ++i) a[i] = at[(r0 + i) * 133 + k];
        const float4 b0 = *(const float4*)(lin2 + (size_t)k * H + c0);
        const float4 b1 = *(const float4*)(lin2 + (size_t)k * H + c0 + 4);
        const float bb[8] = {b0.x, b0.y, b0.z, b0.w, b1.x, b1.y, b1.z, b1.w};
#pragma unroll
        for (int i = 0; i < 2; ++i)
#pragma unroll
            for (int j = 0; j < 8; ++j) acc[i][j] = fmaf(a[i], bb[j], acc[i][j]);
    }
    {
        const float4 q0 = *(const float4*)(b2 + c0);
        const float4 q1 = *(const float4*)(b2 + c0 + 4);
        const float bv[8] = {q0.x, q0.y, q0.z, q0.w, q1.x, q1.y, q1.z, q1.w};
#pragma unroll
        for (int i = 0; i < 2; ++i)
#pragma unroll
            for (int j = 0; j < 8; ++j) acc[i][j] = fast_tanh(acc[i][j] + bv[j]);
    }

    __syncthreads();
#pragma unroll
    for (int i = 0; i < 2; ++i)
#pragma unroll
        for (int j = 0; j < 8; ++j) at[(r0 + i) * 133 + c0 + j] = acc[i][j];
    __syncthreads();

    // stage 2: t @ linw
#pragma unroll
    for (int i = 0; i < 2; ++i)
#pragma unroll
        for (int j = 0; j < 8; ++j) acc[i][j] = 0.0f;

#pragma unroll 4
    for (int k = 0; k < H; ++k) {
        float a[2];
#pragma unroll
        for (int i = 0; i < 2; ++i) a[i] = at[(r0 + i) * 133 + k];
        const float4 b0 = *(const float4*)(linw + (size_t)k * H + c0);
        const float4 b1 = *(const float4*)(linw + (size_t)k * H + c0 + 4);
        const float bb[8] = {b0.x, b0.y, b0.z, b0.w, b1.x, b1.y, b1.z, b1.w};
#pragma unroll
        for (int i = 0; i < 2; ++i)
#pragma unroll
            for (int j = 0; j < 8; ++j) acc[i][j] = fmaf(a[i], bb[j], acc[i][j]);
    }

    {
        const float4 q0 = *(const float4*)(bl + c0);
        const float4 q1 = *(const float4*)(bl + c0 + 4);
        const float bv[8] = {q0.x, q0.y, q0.z, q0.w, q1.x, q1.y, q1.z, q1.w};
        if (MAKE_H) __syncthreads();  // all stage-2 reads of at done before overwrite
#pragma unroll
        for (int ei = 0; ei < 2; ++ei) {
            const int row = abase + r0 + ei;
            float* op = x + (size_t)row * H + c0;
            float4 x0 = *(const float4*)(op);
            float4 x1 = *(const float4*)(op + 4);
            float xn[8] = {x0.x + acc[ei][0] + bv[0], x0.y + acc[ei][1] + bv[1],
                           x0.z + acc[ei][2] + bv[2], x0.w + acc[ei][3] + bv[3],
                           x1.x + acc[ei][4] + bv[4], x1.y + acc[ei][5] + bv[5],
                           x1.z + acc[ei][6] + bv[6], x1.w + acc[ei][7] + bv[7]};
            *(float4*)(op)     = make_float4(xn[0], xn[1], xn[2], xn[3]);
            *(float4*)(op + 4) = make_float4(xn[4], xn[5], xn[6], xn[7]);
            if (MAKE_H) {
#pragma unroll
                for (int j = 0; j < 8; ++j) at[(r0 + ei) * 133 + c0 + j] = xn[j];
            }
        }
    }

    if (MAKE_H) {
        __syncthreads();
        // stage 3: h = x_new @ lin1_next
        float acc3[2][8];
#pragma unroll
        for (int i = 0; i < 2; ++i)
#pragma unroll
            for (int j = 0; j < 8; ++j) acc3[i][j] = 0.0f;

#pragma unroll 4
        for (int k = 0; k < H; ++k) {
            float a[2];
#pragma unroll
            for (int i = 0; i < 2; ++i) a[i] = at[(r0 + i) * 133 + k];
            const float4 b0 = *(const float4*)(lin1n + (size_t)k * H + c0);
            const float4 b1 = *(const float4*)(lin1n + (size_t)k * H + c0 + 4);
            const float bb[8] = {b0.x, b0.y, b0.z, b0.w, b1.x, b1.y, b1.z, b1.w};
#pragma unroll
            for (int i = 0; i < 2; ++i)
#pragma unroll
                for (int j = 0; j < 8; ++j) acc3[i][j] = fmaf(a[i], bb[j], acc3[i][j]);
        }

#pragma unroll
        for (int ei = 0; ei < 2; ++ei) {
            const int row = abase + r0 + ei;
            float* op = hout + (size_t)row * H + c0;
            *(float4*)(op)     = make_float4(acc3[ei][0], acc3[ei][1], acc3[ei][2], acc3[ei][3]);
            *(float4*)(op + 4) = make_float4(acc3[ei][4], acc3[ei][5], acc3[ei][6], acc3[ei][7]);
        }
    }
}

// ---------------- K2: atom-centric gather-aggregate, shfl-broadcast meta ----------------
__global__ __launch_bounds__(256) void k_edge4(const int* __restrict__ rstart,
                                               const int* __restrict__ rend,
                                               const int2* __restrict__ pmeta,
                                               const float* __restrict__ tab,
                                               const float* __restrict__ h,
                                               float* __restrict__ agg) {
    const int wave = threadIdx.x >> 6;
    const int lane = threadIdx.x & 63;
    const int a = blockIdx.x * 4 + wave;
    const int col0 = lane * 2;

    const int s = rstart[a];
    const int n = rend[a] - s;

    float s0 = 0.0f, s1 = 0.0f;
    if (n <= 64) {
        int2 meta = make_int2(0, 0);
        if (lane < n) meta = pmeta[s + lane];
#pragma unroll 2
        for (int e = 0; e < n; ++e) {
            const int src = __shfl(meta.x, e, 64);
            const float u = __int_as_float(__shfl(meta.y, e, 64));
            int i0 = (int)u;
            i0 = (i0 > TBL - 2) ? (TBL - 2) : i0;
            const float f = u - (float)i0;
            const float2 lo = *(const float2*)(tab + (size_t)i0 * H + col0);
            const float2 hi = *(const float2*)(tab + ((size_t)i0 + 1) * H + col0);
            const float2 hv = *(const float2*)(h + (size_t)src * H + col0);
            s0 = fmaf(fmaf(f, hi.x - lo.x, lo.x), hv.x, s0);
            s1 = fmaf(fmaf(f, hi.y - lo.y, lo.y), hv.y, s1);
        }
    } else {
        for (int e = s; e < s + n; ++e) {
            const int2 m = pmeta[e];
            const float u = __int_as_float(m.y);
            int i0 = (int)u;
            i0 = (i0 > TBL - 2) ? (TBL - 2) : i0;
            const float f = u - (float)i0;
            const float2 lo = *(const float2*)(tab + (size_t)i0 * H + col0);
            const float2 hi = *(const float2*)(tab + ((size_t)i0 + 1) * H + col0);
            const float2 hv = *(const float2*)(h + (size_t)m.x * H + col0);
            s0 = fmaf(fmaf(f, hi.x - lo.x, lo.x), hv.x, s0);
            s1 = fmaf(fmaf(f, hi.y - lo.y, lo.y), hv.y, s1);
        }
    }
    *(float2*)(agg + (size_t)a * H + col0) = make_float2(s0, s1);
}

// ---------------- K5: energy, 64 atoms x 64 cols per 256-thread block ----------------
__global__ __launch_bounds__(256) void k_out(const float* __restrict__ x,
                                             const float* __restrict__ o1w,
                                             const float* __restrict__ o1b,
                                             const float* __restrict__ o2w,
                                             const float* __restrict__ o2b,
                                             float* __restrict__ out) {
    __shared__ float xs[64 * 132];
    const int tid = threadIdx.x;
    const int abase = blockIdx.x * 64;

#pragma unroll
    for (int i = 0; i < 8; ++i) {
        int flat4 = tid + 256 * i;
        int r = flat4 >> 5, k4 = flat4 & 31;
        float4 v = ((const float4*)(x + (size_t)(abase + r) * H))[k4];
        float* dp = &xs[r * 132 + k4 * 4];
        dp[0] = v.x; dp[1] = v.y; dp[2] = v.z; dp[3] = v.w;
    }
    __syncthreads();

    const int eg = tid >> 4, cg = tid & 15;
    const int r0 = eg * 4, c0 = cg * 4;

    float acc[4][4];
#pragma unroll
    for (int i = 0; i < 4; ++i)
#pragma unroll
        for (int j = 0; j < 4; ++j) acc[i][j] = 0.0f;

#pragma unroll 4
    for (int k = 0; k < H; ++k) {
        float a[4];
#pragma unroll
        for (int i = 0; i < 4; ++i) a[i] = xs[(r0 + i) * 132 + k];
        const float4 b = *(const float4*)(o1w + (size_t)k * 64 + c0);
        const float bb[4] = {b.x, b.y, b.z, b.w};
#pragma unroll
        for (int i = 0; i < 4; ++i)
#pragma unroll
            for (int j = 0; j < 4; ++j) acc[i][j] = fmaf(a[i], bb[j], acc[i][j]);
    }

    const float4 ob = *(const float4*)(o1b + c0);
    const float4 ow = *(const float4*)(o2w + c0);
    const float obv[4] = {ob.x, ob.y, ob.z, ob.w};
    const float owv[4] = {ow.x, ow.y, ow.z, ow.w};
    float p[4];
#pragma unroll
    for (int i = 0; i < 4; ++i) {
        float s = 0.0f;
#pragma unroll
        for (int j = 0; j < 4; ++j) s = fmaf(fast_tanh(acc[i][j] + obv[j]), owv[j], s);
        p[i] = s;
    }
#pragma unroll
    for (int off = 1; off < 16; off <<= 1) {
#pragma unroll
        for (int i = 0; i < 4; ++i) p[i] += __shfl_xor(p[i], off, 64);
    }
    if (cg == 0) {
        const float b2 = o2b[0];
#pragma unroll
        for (int i = 0; i < 4; ++i) out[abase + r0 + i] = p[i] + b2;
    }
}

extern "C" void kernel_launch(void* const* d_in, const int* in_sizes, int n_in,
                              void* d_out, int out_size, void* d_ws, size_t ws_size,
                              hipStream_t stream) {
    const int*   types = (const int*)d_in[0];
    const int*   eidx  = (const int*)d_in[1];
    const float* ew    = (const float*)d_in[2];
    const float* emb   = (const float*)d_in[3];
    const float* lin1  = (const float*)d_in[4];
    const float* fw1   = (const float*)d_in[5];
    const float* fb1   = (const float*)d_in[6];
    const float* fw2   = (const float*)d_in[7];
    const float* fb2   = (const float*)d_in[8];
    const float* lin2  = (const float*)d_in[9];
    const float* lin2b = (const float*)d_in[10];
    const float* linw  = (const float*)d_in[11];
    const float* linb  = (const float*)d_in[12];
    const float* o1w   = (const float*)d_in[13];
    const float* o1b   = (const float*)d_in[14];
    const float* o2w   = (const float*)d_in[15];
    const float* o2b   = (const float*)d_in[16];
    float* out = (float*)d_out;

    // ws carve
    float* x      = (float*)d_ws;                            // N*H
    float* h      = x + (size_t)N_ATOMS * H;                 // N*H
    float* agg    = h + (size_t)N_ATOMS * H;                 // N*H
    float* tab    = agg + (size_t)N_ATOMS * H;               // NBLK*TBL*H
    float* embw   = tab + (size_t)NBLK * TBL * H;            // 100*H
    int*   cnt    = (int*)(embw + 100 * H);                  // N
    int*   cursor = cnt + N_ATOMS;                           // N
    int*   rstart = cursor + N_ATOMS;                        // N
    int*   bsum   = rstart + N_ATOMS;                        // 40 (pad 64)
    int*   boff   = bsum + 64;                               // 40 (pad 64)
    int2*  pmeta  = (int2*)(boff + 64);                      // E

    // ---- CSR build ----
    hipMemsetAsync(cnt, 0, N_ATOMS * sizeof(int), stream);
    k_count<<<E_EDGES / 256, 256, 0, stream>>>(eidx, cnt);
    k_scanA<<<40, 1024, 0, stream>>>(cnt, bsum);
    k_scanB<<<1, 64, 0, stream>>>(bsum, boff);
    k_scanC<<<40, 1024, 0, stream>>>(cnt, boff, cursor, rstart);
    k_fill<<<E_EDGES / 256, 256, 0, stream>>>(eidx, ew, cursor, pmeta);
    // after k_fill, cursor[a] == row end of atom a

    // ---- type-table h0, embed, filter tables ----
    k_embw<<<100, 128, 0, stream>>>(emb, lin1, embw);
    k_embed2<<<(N_ATOMS * H / 4) / 256, 256, 0, stream>>>(types, emb, embw, x, h);
    k_table<<<dim3(TBL / 128, NBLK), 256, 0, stream>>>(fw1, fb1, fw2, fb2, tab);

    for (int b = 0; b < NBLK; ++b) {
        k_edge4<<<N_ATOMS / 4, 256, 0, stream>>>(rstart, cursor, pmeta,
                                                 tab + (size_t)b * TBL * H, h, agg);
        if (b < NBLK - 1) {
            k_tail<true><<<N_ATOMS / 32, 256, 0, stream>>>(
                agg, lin2 + (size_t)b * H * H, lin2b + (size_t)b * H,
                linw + (size_t)b * H * H, linb + (size_t)b * H, x,
                lin1 + (size_t)(b + 1) * H * H, h);
        } else {
            k_tail<false><<<N_ATOMS / 32, 256, 0, stream>>>(
                agg, lin2 + (size_t)b * H * H, lin2b + (size_t)b * H,
                linw + (size_t)b * H * H, linb + (size_t)b * H, x,
                nullptr, nullptr);
        }
    }

    k_out<<<N_ATOMS / 64, 256, 0, stream>>>(x, o1w, o1b, o2w, o2b, out);
}

// Round 8
// 642.900 us; speedup vs baseline: 1.1582x; 1.1582x over previous
//
#include <hip/hip_runtime.h>
#include <math.h>

#define N_ATOMS 40000
#define E_EDGES 640000
#define H 128
#define RBF 64
#define NBLK 3
#define CUTF 5.0f
#define TBL 4096   // filter lookup table entries per block (2 MB -> L2-resident)

// stable fast tanh: exp-based, saturates correctly at +/-inf
__device__ __forceinline__ float fast_tanh(float x) {
    return 1.0f - 2.0f / (1.0f + __expf(2.0f * x));
}

// ---------------- embW = emb @ lin1[0]  (100 x 128) ----------------
__global__ __launch_bounds__(128) void k_embw(const float* __restrict__ emb,
                                              const float* __restrict__ lin1,
                                              float* __restrict__ embw) {
    const int t = blockIdx.x;
    const int c = threadIdx.x;
    float s = 0.0f;
#pragma unroll 8
    for (int k = 0; k < H; ++k) s = fmaf(emb[t * H + k], lin1[(size_t)k * H + c], s);
    embw[t * H + c] = s;
}

// ---------------- K0: x = emb[atom_types]; h = embW[atom_types] ----------------
__global__ __launch_bounds__(256) void k_embed2(const int* __restrict__ types,
                                                const float* __restrict__ emb,
                                                const float* __restrict__ embw,
                                                float* __restrict__ x,
                                                float* __restrict__ h) {
    int flat4 = blockIdx.x * 256 + threadIdx.x;  // over N*H/4
    int i = flat4 >> 5;
    int c4 = flat4 & 31;
    int t = types[i];
    ((float4*)(x + (size_t)i * H))[c4] = ((const float4*)(emb + (size_t)t * H))[c4];
    ((float4*)(h + (size_t)i * H))[c4] = ((const float4*)(embw + (size_t)t * H))[c4];
}

// ---------------- CSR build ----------------
__global__ __launch_bounds__(256) void k_count(const int* __restrict__ eidx,
                                               int* __restrict__ cnt) {
    int e = blockIdx.x * 256 + threadIdx.x;
    atomicAdd(&cnt[eidx[E_EDGES + e]], 1);
}

__global__ __launch_bounds__(1024) void k_scanA(const int* __restrict__ cnt,
                                                int* __restrict__ bsum) {
    __shared__ int ws[16];
    const int tid = threadIdx.x, lane = tid & 63, wid = tid >> 6;
    int idx = blockIdx.x * 1024 + tid;
    int v = (idx < N_ATOMS) ? cnt[idx] : 0;
#pragma unroll
    for (int off = 32; off; off >>= 1) v += __shfl_xor(v, off, 64);
    if (lane == 0) ws[wid] = v;
    __syncthreads();
    if (tid == 0) {
        int s = 0;
#pragma unroll
        for (int w = 0; w < 16; ++w) s += ws[w];
        bsum[blockIdx.x] = s;
    }
}

__global__ __launch_bounds__(64) void k_scanB(const int* __restrict__ bsum,
                                              int* __restrict__ boff) {
    const int lane = threadIdx.x;
    int v = (lane < 40) ? bsum[lane] : 0;
    int inc = v;
#pragma unroll
    for (int off = 1; off < 64; off <<= 1) {
        int t = __shfl_up(inc, off, 64);
        if (lane >= off) inc += t;
    }
    if (lane < 40) boff[lane] = inc - v;
}

__global__ __launch_bounds__(1024) void k_scanC(const int* __restrict__ cnt,
                                                const int* __restrict__ boff,
                                                int* __restrict__ cursor,
                                                int* __restrict__ rstart) {
    __shared__ int wsum[16];
    __shared__ int woff[16];
    const int tid = threadIdx.x, lane = tid & 63, wid = tid >> 6;
    int idx = blockIdx.x * 1024 + tid;
    int v = (idx < N_ATOMS) ? cnt[idx] : 0;
    int inc = v;
#pragma unroll
    for (int off = 1; off < 64; off <<= 1) {
        int t = __shfl_up(inc, off, 64);
        if (lane >= off) inc += t;
    }
    if (lane == 63) wsum[wid] = inc;
    __syncthreads();
    if (tid == 0) {
        int acc = 0;
#pragma unroll
        for (int w = 0; w < 16; ++w) { woff[w] = acc; acc += wsum[w]; }
    }
    __syncthreads();
    if (idx < N_ATOMS) {
        int ex = boff[blockIdx.x] + woff[wid] + inc - v;
        cursor[idx] = ex;
        rstart[idx] = ex;
    }
}

// fill: pmeta[pos] = {src, float_bits(u)}, u = d*(TBL-1)/CUT (dst-sorted)
__global__ __launch_bounds__(256) void k_fill(const int* __restrict__ eidx,
                                              const float* __restrict__ ew,
                                              int* __restrict__ cursor,
                                              int2* __restrict__ pmeta) {
    int e = blockIdx.x * 256 + threadIdx.x;
    int dd = eidx[E_EDGES + e];
    int pos = atomicAdd(&cursor[dd], 1);
    float u = ew[e] * ((float)(TBL - 1) / CUTF);
    pmeta[pos] = make_int2(eidx[e], __float_as_int(u));
}

// ---------------- K1: filter table build ----------------
__global__ __launch_bounds__(256, 2) void k_table(const float* __restrict__ fw1all,
                                                  const float* __restrict__ fb1all,
                                                  const float* __restrict__ fw2all,
                                                  const float* __restrict__ fb2all,
                                                  float* __restrict__ tab) {
    const int b = blockIdx.y;
    const float* fw1 = fw1all + (size_t)b * RBF * H;
    const float* fb1 = fb1all + (size_t)b * H;
    const float* fw2 = fw2all + (size_t)b * H * H;
    const float* fb2 = fb2all + (size_t)b * H;
    float* tabB = tab + (size_t)b * TBL * H;

    __shared__ float tile[128 * 133];
    const int tid = threadIdx.x;
    const int mbase = blockIdx.x * 128;
    const float DSTEP = CUTF / (float)(TBL - 1);

    {
        const int e = tid & 127;
        const int k0 = (tid >> 7) * 32;
        const float d = (float)(mbase + e) * DSTEP;
        const float DELTA = CUTF / 63.0f;
        const float COEFF = -0.5f / (DELTA * DELTA);
#pragma unroll
        for (int k = k0; k < k0 + 32; ++k) {
            float diff = d - (float)k * DELTA;
            tile[e * 133 + k] = __expf(COEFF * diff * diff);
        }
    }
    __syncthreads();

    const int eg = tid >> 4, cg = tid & 15;
    const int e0 = eg * 8, c0 = cg * 8;

    float acc[8][8];
#pragma unroll
    for (int i = 0; i < 8; ++i)
#pragma unroll
        for (int j = 0; j < 8; ++j) acc[i][j] = 0.0f;

#pragma unroll 4
    for (int k = 0; k < RBF; ++k) {
        float a[8];
#pragma unroll
        for (int i = 0; i < 8; ++i) a[i] = tile[(e0 + i) * 133 + k];
        const float4 b0 = *(const float4*)(fw1 + (size_t)k * H + c0);
        const float4 b1 = *(const float4*)(fw1 + (size_t)k * H + c0 + 4);
        const float bb[8] = {b0.x, b0.y, b0.z, b0.w, b1.x, b1.y, b1.z, b1.w};
#pragma unroll
        for (int i = 0; i < 8; ++i)
#pragma unroll
            for (int j = 0; j < 8; ++j) acc[i][j] = fmaf(a[i], bb[j], acc[i][j]);
    }

    {
        const float4 q0 = *(const float4*)(fb1 + c0);
        const float4 q1 = *(const float4*)(fb1 + c0 + 4);
        const float bv[8] = {q0.x, q0.y, q0.z, q0.w, q1.x, q1.y, q1.z, q1.w};
#pragma unroll
        for (int i = 0; i < 8; ++i)
#pragma unroll
            for (int j = 0; j < 8; ++j) acc[i][j] = fast_tanh(acc[i][j] + bv[j]);
    }

    __syncthreads();
#pragma unroll
    for (int i = 0; i < 8; ++i)
#pragma unroll
        for (int j = 0; j < 8; ++j) tile[(e0 + i) * 133 + c0 + j] = acc[i][j];
    __syncthreads();

#pragma unroll
    for (int i = 0; i < 8; ++i)
#pragma unroll
        for (int j = 0; j < 8; ++j) acc[i][j] = 0.0f;

#pragma unroll 4
    for (int k = 0; k < H; ++k) {
        float a[8];
#pragma unroll
        for (int i = 0; i < 8; ++i) a[i] = tile[(e0 + i) * 133 + k];
        const float4 b0 = *(const float4*)(fw2 + (size_t)k * H + c0);
        const float4 b1 = *(const float4*)(fw2 + (size_t)k * H + c0 + 4);
        const float bb[8] = {b0.x, b0.y, b0.z, b0.w, b1.x, b1.y, b1.z, b1.w};
#pragma unroll
        for (int i = 0; i < 8; ++i)
#pragma unroll
            for (int j = 0; j < 8; ++j) acc[i][j] = fmaf(a[i], bb[j], acc[i][j]);
    }

    const float4 q0 = *(const float4*)(fb2 + c0);
    const float4 q1 = *(const float4*)(fb2 + c0 + 4);
    const float bv[8] = {q0.x, q0.y, q0.z, q0.w, q1.x, q1.y, q1.z, q1.w};

#pragma unroll
    for (int ei = 0; ei < 8; ++ei) {
        const int m = mbase + e0 + ei;
        const float d = (float)m * DSTEP;
        float c = 0.5f * (cosf(0.6283185307179586f * d) + 1.0f);
        c = (d < CUTF) ? c : 0.0f;
        float* op = tabB + (size_t)m * H + c0;
        float r[8];
#pragma unroll
        for (int j = 0; j < 8; ++j) r[j] = (acc[ei][j] + bv[j]) * c;
        *(float4*)(op)     = make_float4(r[0], r[1], r[2], r[3]);
        *(float4*)(op + 4) = make_float4(r[4], r[5], r[6], r[7]);
    }
}

// ---------------- software-pipelined 64x128 @ 128x128 stage ----------------
// A in LDS [64][133]; W streamed from global via register double-buffer
// (rows k,k+1 in set A; k+2,k+3 in set B) so ~2 k-groups of FMAs separate
// load issue from use. All buffer indices static (no scratch).
__device__ __forceinline__ void gemm_pipe(const float* __restrict__ at,
                                          const float* __restrict__ W,
                                          int r0, int c0, float acc[4][8]) {
#pragma unroll
    for (int i = 0; i < 4; ++i)
#pragma unroll
        for (int j = 0; j < 8; ++j) acc[i][j] = 0.0f;

    const float* Wc = W + c0;
    float4 a0l = *(const float4*)(Wc);
    float4 a0h = *(const float4*)(Wc + 4);
    float4 a1l = *(const float4*)(Wc + H);
    float4 a1h = *(const float4*)(Wc + H + 4);

#pragma unroll 2
    for (int k = 0; k < H; k += 4) {
        // issue k+2, k+3 (always in-bounds: k <= 124)
        float4 b0l = *(const float4*)(Wc + (size_t)(k + 2) * H);
        float4 b0h = *(const float4*)(Wc + (size_t)(k + 2) * H + 4);
        float4 b1l = *(const float4*)(Wc + (size_t)(k + 3) * H);
        float4 b1h = *(const float4*)(Wc + (size_t)(k + 3) * H + 4);
        {
            float a[4], b[4];
#pragma unroll
            for (int i = 0; i < 4; ++i) {
                a[i] = at[(r0 + i) * 133 + k];
                b[i] = at[(r0 + i) * 133 + k + 1];
            }
            const float w0[8] = {a0l.x, a0l.y, a0l.z, a0l.w, a0h.x, a0h.y, a0h.z, a0h.w};
            const float w1[8] = {a1l.x, a1l.y, a1l.z, a1l.w, a1h.x, a1h.y, a1h.z, a1h.w};
#pragma unroll
            for (int i = 0; i < 4; ++i)
#pragma unroll
                for (int j = 0; j < 8; ++j) acc[i][j] = fmaf(a[i], w0[j], acc[i][j]);
#pragma unroll
            for (int i = 0; i < 4; ++i)
#pragma unroll
                for (int j = 0; j < 8; ++j) acc[i][j] = fmaf(b[i], w1[j], acc[i][j]);
        }
        // issue k+4, k+5 into set A (wrap to row 0/1 on last group: harmless reload)
        const int kn = (k + 4) & (H - 1);
        a0l = *(const float4*)(Wc + (size_t)kn * H);
        a0h = *(const float4*)(Wc + (size_t)kn * H + 4);
        a1l = *(const float4*)(Wc + (size_t)(kn + 1) * H);
        a1h = *(const float4*)(Wc + (size_t)(kn + 1) * H + 4);
        {
            float a[4], b[4];
#pragma unroll
            for (int i = 0; i < 4; ++i) {
                a[i] = at[(r0 + i) * 133 + k + 2];
                b[i] = at[(r0 + i) * 133 + k + 3];
            }
            const float w0[8] = {b0l.x, b0l.y, b0l.z, b0l.w, b0h.x, b0h.y, b0h.z, b0h.w};
            const float w1[8] = {b1l.x, b1l.y, b1l.z, b1l.w, b1h.x, b1h.y, b1h.z, b1h.w};
#pragma unroll
            for (int i = 0; i < 4; ++i)
#pragma unroll
                for (int j = 0; j < 8; ++j) acc[i][j] = fmaf(a[i], w0[j], acc[i][j]);
#pragma unroll
            for (int i = 0; i < 4; ++i)
#pragma unroll
                for (int j = 0; j < 8; ++j) acc[i][j] = fmaf(b[i], w1[j], acc[i][j]);
        }
    }
}

// ---------------- fused tail (256 thr, 64-atom tile, 4x8 micro, pipelined W):
// x += tanh(agg@lin2+b2)@linw + bl ; optionally h = x_new@lin1_next
template <bool MAKE_H>
__global__ __launch_bounds__(256) void k_tail(const float* __restrict__ agg,
                                              const float* __restrict__ lin2,
                                              const float* __restrict__ b2,
                                              const float* __restrict__ linw,
                                              const float* __restrict__ bl,
                                              float* __restrict__ x,
                                              const float* __restrict__ lin1n,
                                              float* __restrict__ hout) {
    __shared__ float at[64 * 133];
    const int tid = threadIdx.x;
    const int abase = blockIdx.x * 64;

    // stage agg tile [64][128] -> LDS
#pragma unroll
    for (int i = 0; i < 8; ++i) {
        int flat4 = tid + 256 * i;
        int r = flat4 >> 5, k4 = flat4 & 31;
        float4 v = ((const float4*)(agg + (size_t)(abase + r) * H))[k4];
        float* dp = &at[r * 133 + k4 * 4];
        dp[0] = v.x; dp[1] = v.y; dp[2] = v.z; dp[3] = v.w;
    }
    __syncthreads();

    const int eg = tid >> 4, cg = tid & 15;   // 16 x 16 thread grid
    const int r0 = eg * 4, c0 = cg * 8;       // 4 rows x 8 cols per thread

    float acc[4][8];

    // stage 1: tanh(agg @ lin2 + b2)
    gemm_pipe(at, lin2, r0, c0, acc);
    {
        const float4 q0 = *(const float4*)(b2 + c0);
        const float4 q1 = *(const float4*)(b2 + c0 + 4);
        const float bv[8] = {q0.x, q0.y, q0.z, q0.w, q1.x, q1.y, q1.z, q1.w};
#pragma unroll
        for (int i = 0; i < 4; ++i)
#pragma unroll
            for (int j = 0; j < 8; ++j) acc[i][j] = fast_tanh(acc[i][j] + bv[j]);
    }

    __syncthreads();
#pragma unroll
    for (int i = 0; i < 4; ++i)
#pragma unroll
        for (int j = 0; j < 8; ++j) at[(r0 + i) * 133 + c0 + j] = acc[i][j];
    __syncthreads();

    // stage 2: t @ linw ; x += . + bl
    gemm_pipe(at, linw, r0, c0, acc);
    {
        const float4 q0 = *(const float4*)(bl + c0);
        const float4 q1 = *(const float4*)(bl + c0 + 4);
        const float bv[8] = {q0.x, q0.y, q0.z, q0.w, q1.x, q1.y, q1.z, q1.w};
        if (MAKE_H) __syncthreads();  // all stage-2 reads of at done before overwrite
#pragma unroll
        for (int ei = 0; ei < 4; ++ei) {
            const int row = abase + r0 + ei;
            float* op = x + (size_t)row * H + c0;
            float4 x0 = *(const float4*)(op);
            float4 x1 = *(const float4*)(op + 4);
            float xn[8] = {x0.x + acc[ei][0] + bv[0], x0.y + acc[ei][1] + bv[1],
                           x0.z + acc[ei][2] + bv[2], x0.w + acc[ei][3] + bv[3],
                           x1.x + acc[ei][4] + bv[4], x1.y + acc[ei][5] + bv[5],
                           x1.z + acc[ei][6] + bv[6], x1.w + acc[ei][7] + bv[7]};
            *(float4*)(op)     = make_float4(xn[0], xn[1], xn[2], xn[3]);
            *(float4*)(op + 4) = make_float4(xn[4], xn[5], xn[6], xn[7]);
            if (MAKE_H) {
#pragma unroll
                for (int j = 0; j < 8; ++j) at[(r0 + ei) * 133 + c0 + j] = xn[j];
            }
        }
    }

    if (MAKE_H) {
        __syncthreads();
        // stage 3: h = x_new @ lin1_next
        gemm_pipe(at, lin1n, r0, c0, acc);
#pragma unroll
        for (int ei = 0; ei < 4; ++ei) {
            const int row = abase + r0 + ei;
            float* op = hout + (size_t)row * H + c0;
            *(float4*)(op)     = make_float4(acc[ei][0], acc[ei][1], acc[ei][2], acc[ei][3]);
            *(float4*)(op + 4) = make_float4(acc[ei][4], acc[ei][5], acc[ei][6], acc[ei][7]);
        }
    }
}

// ---------------- K2: atom-centric gather-aggregate, shfl-broadcast meta ----------------
__global__ __launch_bounds__(256) void k_edge4(const int* __restrict__ rstart,
                                               const int* __restrict__ rend,
                                               const int2* __restrict__ pmeta,
                                               const float* __restrict__ tab,
                                               const float* __restrict__ h,
                                               float* __restrict__ agg) {
    const int wave = threadIdx.x >> 6;
    const int lane = threadIdx.x & 63;
    const int a = blockIdx.x * 4 + wave;
    const int col0 = lane * 2;

    const int s = rstart[a];
    const int n = rend[a] - s;

    float s0 = 0.0f, s1 = 0.0f;
    if (n <= 64) {
        int2 meta = make_int2(0, 0);
        if (lane < n) meta = pmeta[s + lane];
#pragma unroll 2
        for (int e = 0; e < n; ++e) {
            const int src = __shfl(meta.x, e, 64);
            const float u = __int_as_float(__shfl(meta.y, e, 64));
            int i0 = (int)u;
            i0 = (i0 > TBL - 2) ? (TBL - 2) : i0;
            const float f = u - (float)i0;
            const float2 lo = *(const float2*)(tab + (size_t)i0 * H + col0);
            const float2 hi = *(const float2*)(tab + ((size_t)i0 + 1) * H + col0);
            const float2 hv = *(const float2*)(h + (size_t)src * H + col0);
            s0 = fmaf(fmaf(f, hi.x - lo.x, lo.x), hv.x, s0);
            s1 = fmaf(fmaf(f, hi.y - lo.y, lo.y), hv.y, s1);
        }
    } else {
        for (int e = s; e < s + n; ++e) {
            const int2 m = pmeta[e];
            const float u = __int_as_float(m.y);
            int i0 = (int)u;
            i0 = (i0 > TBL - 2) ? (TBL - 2) : i0;
            const float f = u - (float)i0;
            const float2 lo = *(const float2*)(tab + (size_t)i0 * H + col0);
            const float2 hi = *(const float2*)(tab + ((size_t)i0 + 1) * H + col0);
            const float2 hv = *(const float2*)(h + (size_t)m.x * H + col0);
            s0 = fmaf(fmaf(f, hi.x - lo.x, lo.x), hv.x, s0);
            s1 = fmaf(fmaf(f, hi.y - lo.y, lo.y), hv.y, s1);
        }
    }
    *(float2*)(agg + (size_t)a * H + col0) = make_float2(s0, s1);
}

// ---------------- K5: energy, 64 atoms x 64 cols per 256-thread block ----------------
__global__ __launch_bounds__(256) void k_out(const float* __restrict__ x,
                                             const float* __restrict__ o1w,
                                             const float* __restrict__ o1b,
                                             const float* __restrict__ o2w,
                                             const float* __restrict__ o2b,
                                             float* __restrict__ out) {
    __shared__ float xs[64 * 132];
    const int tid = threadIdx.x;
    const int abase = blockIdx.x * 64;

#pragma unroll
    for (int i = 0; i < 8; ++i) {
        int flat4 = tid + 256 * i;
        int r = flat4 >> 5, k4 = flat4 & 31;
        float4 v = ((const float4*)(x + (size_t)(abase + r) * H))[k4];
        float* dp = &xs[r * 132 + k4 * 4];
        dp[0] = v.x; dp[1] = v.y; dp[2] = v.z; dp[3] = v.w;
    }
    __syncthreads();

    const int eg = tid >> 4, cg = tid & 15;
    const int r0 = eg * 4, c0 = cg * 4;

    float acc[4][4];
#pragma unroll
    for (int i = 0; i < 4; ++i)
#pragma unroll
        for (int j = 0; j < 4; ++j) acc[i][j] = 0.0f;

#pragma unroll 4
    for (int k = 0; k < H; ++k) {
        float a[4];
#pragma unroll
        for (int i = 0; i < 4; ++i) a[i] = xs[(r0 + i) * 132 + k];
        const float4 b = *(const float4*)(o1w + (size_t)k * 64 + c0);
        const float bb[4] = {b.x, b.y, b.z, b.w};
#pragma unroll
        for (int i = 0; i < 4; ++i)
#pragma unroll
            for (int j = 0; j < 4; ++j) acc[i][j] = fmaf(a[i], bb[j], acc[i][j]);
    }

    const float4 ob = *(const float4*)(o1b + c0);
    const float4 ow = *(const float4*)(o2w + c0);
    const float obv[4] = {ob.x, ob.y, ob.z, ob.w};
    const float owv[4] = {ow.x, ow.y, ow.z, ow.w};
    float p[4];
#pragma unroll
    for (int i = 0; i < 4; ++i) {
        float s = 0.0f;
#pragma unroll
        for (int j = 0; j < 4; ++j) s = fmaf(fast_tanh(acc[i][j] + obv[j]), owv[j], s);
        p[i] = s;
    }
#pragma unroll
    for (int off = 1; off < 16; off <<= 1) {
#pragma unroll
        for (int i = 0; i < 4; ++i) p[i] += __shfl_xor(p[i], off, 64);
    }
    if (cg == 0) {
        const float b2 = o2b[0];
#pragma unroll
        for (int i = 0; i < 4; ++i) out[abase + r0 + i] = p[i] + b2;
    }
}

extern "C" void kernel_launch(void* const* d_in, const int* in_sizes, int n_in,
                              void* d_out, int out_size, void* d_ws, size_t ws_size,
                              hipStream_t stream) {
    const int*   types = (const int*)d_in[0];
    const int*   eidx  = (const int*)d_in[1];
    const float* ew    = (const float*)d_in[2];
    const float* emb   = (const float*)d_in[3];
    const float* lin1  = (const float*)d_in[4];
    const float* fw1   = (const float*)d_in[5];
    const float* fb1   = (const float*)d_in[6];
    const float* fw2   = (const float*)d_in[7];
    const float* fb2   = (const float*)d_in[8];
    const float* lin2  = (const float*)d_in[9];
    const float* lin2b = (const float*)d_in[10];
    const float* linw  = (const float*)d_in[11];
    const float* linb  = (const float*)d_in[12];
    const float* o1w   = (const float*)d_in[13];
    const float* o1b   = (const float*)d_in[14];
    const float* o2w   = (const float*)d_in[15];
    const float* o2b   = (const float*)d_in[16];
    float* out = (float*)d_out;

    // ws carve
    float* x      = (float*)d_ws;                            // N*H
    float* h      = x + (size_t)N_ATOMS * H;                 // N*H
    float* agg    = h + (size_t)N_ATOMS * H;                 // N*H
    float* tab    = agg + (size_t)N_ATOMS * H;               // NBLK*TBL*H
    float* embw   = tab + (size_t)NBLK * TBL * H;            // 100*H
    int*   cnt    = (int*)(embw + 100 * H);                  // N
    int*   cursor = cnt + N_ATOMS;                           // N
    int*   rstart = cursor + N_ATOMS;                        // N
    int*   bsum   = rstart + N_ATOMS;                        // 40 (pad 64)
    int*   boff   = bsum + 64;                               // 40 (pad 64)
    int2*  pmeta  = (int2*)(boff + 64);                      // E

    // ---- CSR build ----
    hipMemsetAsync(cnt, 0, N_ATOMS * sizeof(int), stream);
    k_count<<<E_EDGES / 256, 256, 0, stream>>>(eidx, cnt);
    k_scanA<<<40, 1024, 0, stream>>>(cnt, bsum);
    k_scanB<<<1, 64, 0, stream>>>(bsum, boff);
    k_scanC<<<40, 1024, 0, stream>>>(cnt, boff, cursor, rstart);
    k_fill<<<E_EDGES / 256, 256, 0, stream>>>(eidx, ew, cursor, pmeta);
    // after k_fill, cursor[a] == row end of atom a

    // ---- type-table h0, embed, filter tables ----
    k_embw<<<100, 128, 0, stream>>>(emb, lin1, embw);
    k_embed2<<<(N_ATOMS * H / 4) / 256, 256, 0, stream>>>(types, emb, embw, x, h);
    k_table<<<dim3(TBL / 128, NBLK), 256, 0, stream>>>(fw1, fb1, fw2, fb2, tab);

    for (int b = 0; b < NBLK; ++b) {
        k_edge4<<<N_ATOMS / 4, 256, 0, stream>>>(rstart, cursor, pmeta,
                                                 tab + (size_t)b * TBL * H, h, agg);
        if (b < NBLK - 1) {
            k_tail<true><<<N_ATOMS / 64, 256, 0, stream>>>(
                agg, lin2 + (size_t)b * H * H, lin2b + (size_t)b * H,
                linw + (size_t)b * H * H, linb + (size_t)b * H, x,
                lin1 + (size_t)(b + 1) * H * H, h);
        } else {
            k_tail<false><<<N_ATOMS / 64, 256, 0, stream>>>(
                agg, lin2 + (size_t)b * H * H, lin2b + (size_t)b * H,
                linw + (size_t)b * H * H, linb + (size_t)b * H, x,
                nullptr, nullptr);
        }
    }

    k_out<<<N_ATOMS / 64, 256, 0, stream>>>(x, o1w, o1b, o2w, o2b, out);
}

// Round 9
// 638.438 us; speedup vs baseline: 1.1663x; 1.0070x over previous
//
#include <hip/hip_runtime.h>
#include <math.h>

#define N_ATOMS 40000
#define E_EDGES 640000
#define H 128
#define RBF 64
#define NBLK 3
#define CUTF 5.0f
#define TBL 4096   // filter lookup table entries per block (2 MB -> L2-resident)

// stable fast tanh: exp-based, saturates correctly at +/-inf
__device__ __forceinline__ float fast_tanh(float x) {
    return 1.0f - 2.0f / (1.0f + __expf(2.0f * x));
}

// ---------------- embW = emb @ lin1[0]  (100 x 128) ----------------
__global__ __launch_bounds__(128) void k_embw(const float* __restrict__ emb,
                                              const float* __restrict__ lin1,
                                              float* __restrict__ embw) {
    const int t = blockIdx.x;
    const int c = threadIdx.x;
    float s = 0.0f;
#pragma unroll 8
    for (int k = 0; k < H; ++k) s = fmaf(emb[t * H + k], lin1[(size_t)k * H + c], s);
    embw[t * H + c] = s;
}

// ---------------- K0: x = emb[atom_types]; h = embW[atom_types] ----------------
__global__ __launch_bounds__(256) void k_embed2(const int* __restrict__ types,
                                                const float* __restrict__ emb,
                                                const float* __restrict__ embw,
                                                float* __restrict__ x,
                                                float* __restrict__ h) {
    int flat4 = blockIdx.x * 256 + threadIdx.x;  // over N*H/4
    int i = flat4 >> 5;
    int c4 = flat4 & 31;
    int t = types[i];
    ((float4*)(x + (size_t)i * H))[c4] = ((const float4*)(emb + (size_t)t * H))[c4];
    ((float4*)(h + (size_t)i * H))[c4] = ((const float4*)(embw + (size_t)t * H))[c4];
}

// ---------------- CSR build ----------------
__global__ __launch_bounds__(256) void k_count(const int* __restrict__ eidx,
                                               int* __restrict__ cnt) {
    int e = blockIdx.x * 256 + threadIdx.x;
    atomicAdd(&cnt[eidx[E_EDGES + e]], 1);
}

__global__ __launch_bounds__(1024) void k_scanA(const int* __restrict__ cnt,
                                                int* __restrict__ bsum) {
    __shared__ int ws[16];
    const int tid = threadIdx.x, lane = tid & 63, wid = tid >> 6;
    int idx = blockIdx.x * 1024 + tid;
    int v = (idx < N_ATOMS) ? cnt[idx] : 0;
#pragma unroll
    for (int off = 32; off; off >>= 1) v += __shfl_xor(v, off, 64);
    if (lane == 0) ws[wid] = v;
    __syncthreads();
    if (tid == 0) {
        int s = 0;
#pragma unroll
        for (int w = 0; w < 16; ++w) s += ws[w];
        bsum[blockIdx.x] = s;
    }
}

__global__ __launch_bounds__(64) void k_scanB(const int* __restrict__ bsum,
                                              int* __restrict__ boff) {
    const int lane = threadIdx.x;
    int v = (lane < 40) ? bsum[lane] : 0;
    int inc = v;
#pragma unroll
    for (int off = 1; off < 64; off <<= 1) {
        int t = __shfl_up(inc, off, 64);
        if (lane >= off) inc += t;
    }
    if (lane < 40) boff[lane] = inc - v;
}

__global__ __launch_bounds__(1024) void k_scanC(const int* __restrict__ cnt,
                                                const int* __restrict__ boff,
                                                int* __restrict__ cursor,
                                                int* __restrict__ rstart) {
    __shared__ int wsum[16];
    __shared__ int woff[16];
    const int tid = threadIdx.x, lane = tid & 63, wid = tid >> 6;
    int idx = blockIdx.x * 1024 + tid;
    int v = (idx < N_ATOMS) ? cnt[idx] : 0;
    int inc = v;
#pragma unroll
    for (int off = 1; off < 64; off <<= 1) {
        int t = __shfl_up(inc, off, 64);
        if (lane >= off) inc += t;
    }
    if (lane == 63) wsum[wid] = inc;
    __syncthreads();
    if (tid == 0) {
        int acc = 0;
#pragma unroll
        for (int w = 0; w < 16; ++w) { woff[w] = acc; acc += wsum[w]; }
    }
    __syncthreads();
    if (idx < N_ATOMS) {
        int ex = boff[blockIdx.x] + woff[wid] + inc - v;
        cursor[idx] = ex;
        rstart[idx] = ex;
    }
}

// fill: pmeta[pos] = {src, float_bits(u)}, u = d*(TBL-1)/CUT (dst-sorted)
__global__ __launch_bounds__(256) void k_fill(const int* __restrict__ eidx,
                                              const float* __restrict__ ew,
                                              int* __restrict__ cursor,
                                              int2* __restrict__ pmeta) {
    int e = blockIdx.x * 256 + threadIdx.x;
    int dd = eidx[E_EDGES + e];
    int pos = atomicAdd(&cursor[dd], 1);
    float u = ew[e] * ((float)(TBL - 1) / CUTF);
    pmeta[pos] = make_int2(eidx[e], __float_as_int(u));
}

// ---------------- K1: filter table build ----------------
__global__ __launch_bounds__(256, 2) void k_table(const float* __restrict__ fw1all,
                                                  const float* __restrict__ fb1all,
                                                  const float* __restrict__ fw2all,
                                                  const float* __restrict__ fb2all,
                                                  float* __restrict__ tab) {
    const int b = blockIdx.y;
    const float* fw1 = fw1all + (size_t)b * RBF * H;
    const float* fb1 = fb1all + (size_t)b * H;
    const float* fw2 = fw2all + (size_t)b * H * H;
    const float* fb2 = fb2all + (size_t)b * H;
    float* tabB = tab + (size_t)b * TBL * H;

    __shared__ float tile[128 * 133];
    const int tid = threadIdx.x;
    const int mbase = blockIdx.x * 128;
    const float DSTEP = CUTF / (float)(TBL - 1);

    {
        const int e = tid & 127;
        const int k0 = (tid >> 7) * 32;
        const float d = (float)(mbase + e) * DSTEP;
        const float DELTA = CUTF / 63.0f;
        const float COEFF = -0.5f / (DELTA * DELTA);
#pragma unroll
        for (int k = k0; k < k0 + 32; ++k) {
            float diff = d - (float)k * DELTA;
            tile[e * 133 + k] = __expf(COEFF * diff * diff);
        }
    }
    __syncthreads();

    const int eg = tid >> 4, cg = tid & 15;
    const int e0 = eg * 8, c0 = cg * 8;

    float acc[8][8];
#pragma unroll
    for (int i = 0; i < 8; ++i)
#pragma unroll
        for (int j = 0; j < 8; ++j) acc[i][j] = 0.0f;

#pragma unroll 4
    for (int k = 0; k < RBF; ++k) {
        float a[8];
#pragma unroll
        for (int i = 0; i < 8; ++i) a[i] = tile[(e0 + i) * 133 + k];
        const float4 b0 = *(const float4*)(fw1 + (size_t)k * H + c0);
        const float4 b1 = *(const float4*)(fw1 + (size_t)k * H + c0 + 4);
        const float bb[8] = {b0.x, b0.y, b0.z, b0.w, b1.x, b1.y, b1.z, b1.w};
#pragma unroll
        for (int i = 0; i < 8; ++i)
#pragma unroll
            for (int j = 0; j < 8; ++j) acc[i][j] = fmaf(a[i], bb[j], acc[i][j]);
    }

    {
        const float4 q0 = *(const float4*)(fb1 + c0);
        const float4 q1 = *(const float4*)(fb1 + c0 + 4);
        const float bv[8] = {q0.x, q0.y, q0.z, q0.w, q1.x, q1.y, q1.z, q1.w};
#pragma unroll
        for (int i = 0; i < 8; ++i)
#pragma unroll
            for (int j = 0; j < 8; ++j) acc[i][j] = fast_tanh(acc[i][j] + bv[j]);
    }

    __syncthreads();
#pragma unroll
    for (int i = 0; i < 8; ++i)
#pragma unroll
        for (int j = 0; j < 8; ++j) tile[(e0 + i) * 133 + c0 + j] = acc[i][j];
    __syncthreads();

#pragma unroll
    for (int i = 0; i < 8; ++i)
#pragma unroll
        for (int j = 0; j < 8; ++j) acc[i][j] = 0.0f;

#pragma unroll 4
    for (int k = 0; k < H; ++k) {
        float a[8];
#pragma unroll
        for (int i = 0; i < 8; ++i) a[i] = tile[(e0 + i) * 133 + k];
        const float4 b0 = *(const float4*)(fw2 + (size_t)k * H + c0);
        const float4 b1 = *(const float4*)(fw2 + (size_t)k * H + c0 + 4);
        const float bb[8] = {b0.x, b0.y, b0.z, b0.w, b1.x, b1.y, b1.z, b1.w};
#pragma unroll
        for (int i = 0; i < 8; ++i)
#pragma unroll
            for (int j = 0; j < 8; ++j) acc[i][j] = fmaf(a[i], bb[j], acc[i][j]);
    }

    const float4 q0 = *(const float4*)(fb2 + c0);
    const float4 q1 = *(const float4*)(fb2 + c0 + 4);
    const float bv[8] = {q0.x, q0.y, q0.z, q0.w, q1.x, q1.y, q1.z, q1.w};

#pragma unroll
    for (int ei = 0; ei < 8; ++ei) {
        const int m = mbase + e0 + ei;
        const float d = (float)m * DSTEP;
        float c = 0.5f * (cosf(0.6283185307179586f * d) + 1.0f);
        c = (d < CUTF) ? c : 0.0f;
        float* op = tabB + (size_t)m * H + c0;
        float r[8];
#pragma unroll
        for (int j = 0; j < 8; ++j) r[j] = (acc[ei][j] + bv[j]) * c;
        *(float4*)(op)     = make_float4(r[0], r[1], r[2], r[3]);
        *(float4*)(op + 4) = make_float4(r[4], r[5], r[6], r[7]);
    }
}

// ---------------- LDS-staged weight panels for the tail GEMMs ----------------
// Panel = 32 rows x 128 cols of W (16 KB), loaded by global_load_lds width-16
// (wave-uniform LDS base + lane*16; per-lane global src). Double-buffered.
__device__ __forceinline__ void stage_panel(const float* __restrict__ Wg,
                                            float* wbuf, int tid) {
    const int w = tid >> 6, lane = tid & 63;
#pragma unroll
    for (int i = 0; i < 4; ++i) {
        const float* g = Wg + ((w << 2) + i) * 256 + (lane << 2);
        float* l = wbuf + ((w << 2) + i) * 256;   // uniform across the wave
        __builtin_amdgcn_global_load_lds((const __attribute__((address_space(1))) void*)g,
                                         (__attribute__((address_space(3))) void*)l,
                                         16, 0, 0);
    }
}

// acc += A(64x128 in LDS, stride 132) @ W(128x128 global, staged via LDS panels)
// __syncthreads() per panel drains vmcnt (compiler semantics) -> next panel ready.
__device__ __forceinline__ void gemm_lds(const float* __restrict__ at,
                                         const float* __restrict__ Wg,
                                         float* __restrict__ wb0,
                                         float* __restrict__ wb1,
                                         int tid, int r0, int c0, float acc[4][8]) {
#pragma unroll
    for (int i = 0; i < 4; ++i)
#pragma unroll
        for (int j = 0; j < 8; ++j) acc[i][j] = 0.0f;

    stage_panel(Wg, wb0, tid);
    __syncthreads();   // panel 0 resident (also covers at[] staging before 1st call)

#pragma unroll
    for (int p = 0; p < 4; ++p) {
        float* cur = (p & 1) ? wb1 : wb0;
        float* nxt = (p & 1) ? wb0 : wb1;
        if (p < 3) stage_panel(Wg + (size_t)(p + 1) * 32 * H, nxt, tid);
        const int kb = p * 32;
#pragma unroll
        for (int k4 = 0; k4 < 32; k4 += 4) {
            float4 av[4];
#pragma unroll
            for (int i = 0; i < 4; ++i)
                av[i] = *(const float4*)&at[(r0 + i) * 132 + kb + k4];
            const float* avf = (const float*)av;   // all indices compile-time after unroll
#pragma unroll
            for (int kk = 0; kk < 4; ++kk) {
                const float4 w0 = *(const float4*)&cur[(k4 + kk) * H + c0];
                const float4 w1 = *(const float4*)&cur[(k4 + kk) * H + c0 + 4];
                const float wv[8] = {w0.x, w0.y, w0.z, w0.w, w1.x, w1.y, w1.z, w1.w};
#pragma unroll
                for (int i = 0; i < 4; ++i) {
                    const float a = avf[i * 4 + kk];
#pragma unroll
                    for (int j = 0; j < 8; ++j) acc[i][j] = fmaf(a, wv[j], acc[i][j]);
                }
            }
        }
        __syncthreads();   // all reads of cur done; next panel's loads landed
    }
}

// ---------------- fused tail (256 thr, 64-atom tile, 4x8 micro, LDS-W panels):
// x += tanh(agg@lin2+b2)@linw + bl ; optionally h = x_new@lin1_next
template <bool MAKE_H>
__global__ __launch_bounds__(256) void k_tail(const float* __restrict__ agg,
                                              const float* __restrict__ lin2,
                                              const float* __restrict__ b2,
                                              const float* __restrict__ linw,
                                              const float* __restrict__ bl,
                                              float* __restrict__ x,
                                              const float* __restrict__ lin1n,
                                              float* __restrict__ hout) {
    __shared__ float at[64 * 132];
    __shared__ float wpan0[32 * H];
    __shared__ float wpan1[32 * H];
    const int tid = threadIdx.x;
    const int abase = blockIdx.x * 64;

    // stage agg tile [64][128] -> LDS (stride 132: 16B-aligned rows for b128 reads)
#pragma unroll
    for (int i = 0; i < 8; ++i) {
        int flat4 = tid + 256 * i;
        int r = flat4 >> 5, k4 = flat4 & 31;
        float4 v = ((const float4*)(agg + (size_t)(abase + r) * H))[k4];
        *(float4*)&at[r * 132 + k4 * 4] = v;
    }
    // no barrier needed: gemm_lds's prologue __syncthreads covers visibility

    const int eg = tid >> 4, cg = tid & 15;   // 16 x 16 thread grid
    const int r0 = eg * 4, c0 = cg * 8;       // 4 rows x 8 cols per thread

    float acc[4][8];

    // stage 1: tanh(agg @ lin2 + b2)
    gemm_lds(at, lin2, wpan0, wpan1, tid, r0, c0, acc);
    {
        const float4 q0 = *(const float4*)(b2 + c0);
        const float4 q1 = *(const float4*)(b2 + c0 + 4);
        const float bv[8] = {q0.x, q0.y, q0.z, q0.w, q1.x, q1.y, q1.z, q1.w};
#pragma unroll
        for (int i = 0; i < 4; ++i)
#pragma unroll
            for (int j = 0; j < 8; ++j) acc[i][j] = fast_tanh(acc[i][j] + bv[j]);
    }
    // write t tile (thread-exclusive region; gemm's final barrier synced everyone)
#pragma unroll
    for (int i = 0; i < 4; ++i)
#pragma unroll
        for (int j = 0; j < 8; ++j) at[(r0 + i) * 132 + c0 + j] = acc[i][j];
    __syncthreads();

    // stage 2: t @ linw ; x += . + bl
    gemm_lds(at, linw, wpan0, wpan1, tid, r0, c0, acc);
    {
        const float4 q0 = *(const float4*)(bl + c0);
        const float4 q1 = *(const float4*)(bl + c0 + 4);
        const float bv[8] = {q0.x, q0.y, q0.z, q0.w, q1.x, q1.y, q1.z, q1.w};
#pragma unroll
        for (int ei = 0; ei < 4; ++ei) {
            const int row = abase + r0 + ei;
            float* op = x + (size_t)row * H + c0;
            float4 x0 = *(const float4*)(op);
            float4 x1 = *(const float4*)(op + 4);
            float xn[8] = {x0.x + acc[ei][0] + bv[0], x0.y + acc[ei][1] + bv[1],
                           x0.z + acc[ei][2] + bv[2], x0.w + acc[ei][3] + bv[3],
                           x1.x + acc[ei][4] + bv[4], x1.y + acc[ei][5] + bv[5],
                           x1.z + acc[ei][6] + bv[6], x1.w + acc[ei][7] + bv[7]};
            *(float4*)(op)     = make_float4(xn[0], xn[1], xn[2], xn[3]);
            *(float4*)(op + 4) = make_float4(xn[4], xn[5], xn[6], xn[7]);
            if (MAKE_H) {
#pragma unroll
                for (int j = 0; j < 8; ++j) at[(r0 + ei) * 132 + c0 + j] = xn[j];
            }
        }
    }

    if (MAKE_H) {
        __syncthreads();
        // stage 3: h = x_new @ lin1_next
        gemm_lds(at, lin1n, wpan0, wpan1, tid, r0, c0, acc);
#pragma unroll
        for (int ei = 0; ei < 4; ++ei) {
            const int row = abase + r0 + ei;
            float* op = hout + (size_t)row * H + c0;
            *(float4*)(op)     = make_float4(acc[ei][0], acc[ei][1], acc[ei][2], acc[ei][3]);
            *(float4*)(op + 4) = make_float4(acc[ei][4], acc[ei][5], acc[ei][6], acc[ei][7]);
        }
    }
}

// ---------------- K2: atom-centric gather-aggregate, shfl-broadcast meta ----------------
__global__ __launch_bounds__(256) void k_edge4(const int* __restrict__ rstart,
                                               const int* __restrict__ rend,
                                               const int2* __restrict__ pmeta,
                                               const float* __restrict__ tab,
                                               const float* __restrict__ h,
                                               float* __restrict__ agg) {
    const int wave = threadIdx.x >> 6;
    const int lane = threadIdx.x & 63;
    const int a = blockIdx.x * 4 + wave;
    const int col0 = lane * 2;

    const int s = rstart[a];
    const int n = rend[a] - s;

    float s0 = 0.0f, s1 = 0.0f;
    if (n <= 64) {
        int2 meta = make_int2(0, 0);
        if (lane < n) meta = pmeta[s + lane];
#pragma unroll 2
        for (int e = 0; e < n; ++e) {
            const int src = __shfl(meta.x, e, 64);
            const float u = __int_as_float(__shfl(meta.y, e, 64));
            int i0 = (int)u;
            i0 = (i0 > TBL - 2) ? (TBL - 2) : i0;
            const float f = u - (float)i0;
            const float2 lo = *(const float2*)(tab + (size_t)i0 * H + col0);
            const float2 hi = *(const float2*)(tab + ((size_t)i0 + 1) * H + col0);
            const float2 hv = *(const float2*)(h + (size_t)src * H + col0);
            s0 = fmaf(fmaf(f, hi.x - lo.x, lo.x), hv.x, s0);
            s1 = fmaf(fmaf(f, hi.y - lo.y, lo.y), hv.y, s1);
        }
    } else {
        for (int e = s; e < s + n; ++e) {
            const int2 m = pmeta[e];
            const float u = __int_as_float(m.y);
            int i0 = (int)u;
            i0 = (i0 > TBL - 2) ? (TBL - 2) : i0;
            const float f = u - (float)i0;
            const float2 lo = *(const float2*)(tab + (size_t)i0 * H + col0);
            const float2 hi = *(const float2*)(tab + ((size_t)i0 + 1) * H + col0);
            const float2 hv = *(const float2*)(h + (size_t)m.x * H + col0);
            s0 = fmaf(fmaf(f, hi.x - lo.x, lo.x), hv.x, s0);
            s1 = fmaf(fmaf(f, hi.y - lo.y, lo.y), hv.y, s1);
        }
    }
    *(float2*)(agg + (size_t)a * H + col0) = make_float2(s0, s1);
}

// ---------------- K5: energy, 64 atoms x 64 cols per 256-thread block ----------------
__global__ __launch_bounds__(256) void k_out(const float* __restrict__ x,
                                             const float* __restrict__ o1w,
                                             const float* __restrict__ o1b,
                                             const float* __restrict__ o2w,
                                             const float* __restrict__ o2b,
                                             float* __restrict__ out) {
    __shared__ float xs[64 * 132];
    const int tid = threadIdx.x;
    const int abase = blockIdx.x * 64;

#pragma unroll
    for (int i = 0; i < 8; ++i) {
        int flat4 = tid + 256 * i;
        int r = flat4 >> 5, k4 = flat4 & 31;
        float4 v = ((const float4*)(x + (size_t)(abase + r) * H))[k4];
        float* dp = &xs[r * 132 + k4 * 4];
        dp[0] = v.x; dp[1] = v.y; dp[2] = v.z; dp[3] = v.w;
    }
    __syncthreads();

    const int eg = tid >> 4, cg = tid & 15;
    const int r0 = eg * 4, c0 = cg * 4;

    float acc[4][4];
#pragma unroll
    for (int i = 0; i < 4; ++i)
#pragma unroll
        for (int j = 0; j < 4; ++j) acc[i][j] = 0.0f;

#pragma unroll 4
    for (int k = 0; k < H; ++k) {
        float a[4];
#pragma unroll
        for (int i = 0; i < 4; ++i) a[i] = xs[(r0 + i) * 132 + k];
        const float4 b = *(const float4*)(o1w + (size_t)k * 64 + c0);
        const float bb[4] = {b.x, b.y, b.z, b.w};
#pragma unroll
        for (int i = 0; i < 4; ++i)
#pragma unroll
            for (int j = 0; j < 4; ++j) acc[i][j] = fmaf(a[i], bb[j], acc[i][j]);
    }

    const float4 ob = *(const float4*)(o1b + c0);
    const float4 ow = *(const float4*)(o2w + c0);
    const float obv[4] = {ob.x, ob.y, ob.z, ob.w};
    const float owv[4] = {ow.x, ow.y, ow.z, ow.w};
    float p[4];
#pragma unroll
    for (int i = 0; i < 4; ++i) {
        float s = 0.0f;
#pragma unroll
        for (int j = 0; j < 4; ++j) s = fmaf(fast_tanh(acc[i][j] + obv[j]), owv[j], s);
        p[i] = s;
    }
#pragma unroll
    for (int off = 1; off < 16; off <<= 1) {
#pragma unroll
        for (int i = 0; i < 4; ++i) p[i] += __shfl_xor(p[i], off, 64);
    }
    if (cg == 0) {
        const float b2 = o2b[0];
#pragma unroll
        for (int i = 0; i < 4; ++i) out[abase + r0 + i] = p[i] + b2;
    }
}

extern "C" void kernel_launch(void* const* d_in, const int* in_sizes, int n_in,
                              void* d_out, int out_size, void* d_ws, size_t ws_size,
                              hipStream_t stream) {
    const int*   types = (const int*)d_in[0];
    const int*   eidx  = (const int*)d_in[1];
    const float* ew    = (const float*)d_in[2];
    const float* emb   = (const float*)d_in[3];
    const float* lin1  = (const float*)d_in[4];
    const float* fw1   = (const float*)d_in[5];
    const float* fb1   = (const float*)d_in[6];
    const float* fw2   = (const float*)d_in[7];
    const float* fb2   = (const float*)d_in[8];
    const float* lin2  = (const float*)d_in[9];
    const float* lin2b = (const float*)d_in[10];
    const float* linw  = (const float*)d_in[11];
    const float* linb  = (const float*)d_in[12];
    const float* o1w   = (const float*)d_in[13];
    const float* o1b   = (const float*)d_in[14];
    const float* o2w   = (const float*)d_in[15];
    const float* o2b   = (const float*)d_in[16];
    float* out = (float*)d_out;

    // ws carve
    float* x      = (float*)d_ws;                            // N*H
    float* h      = x + (size_t)N_ATOMS * H;                 // N*H
    float* agg    = h + (size_t)N_ATOMS * H;                 // N*H
    float* tab    = agg + (size_t)N_ATOMS * H;               // NBLK*TBL*H
    float* embw   = tab + (size_t)NBLK * TBL * H;            // 100*H
    int*   cnt    = (int*)(embw + 100 * H);                  // N
    int*   cursor = cnt + N_ATOMS;                           // N
    int*   rstart = cursor + N_ATOMS;                        // N
    int*   bsum   = rstart + N_ATOMS;                        // 40 (pad 64)
    int*   boff   = bsum + 64;                               // 40 (pad 64)
    int2*  pmeta  = (int2*)(boff + 64);                      // E

    // ---- CSR build ----
    hipMemsetAsync(cnt, 0, N_ATOMS * sizeof(int), stream);
    k_count<<<E_EDGES / 256, 256, 0, stream>>>(eidx, cnt);
    k_scanA<<<40, 1024, 0, stream>>>(cnt, bsum);
    k_scanB<<<1, 64, 0, stream>>>(bsum, boff);
    k_scanC<<<40, 1024, 0, stream>>>(cnt, boff, cursor, rstart);
    k_fill<<<E_EDGES / 256, 256, 0, stream>>>(eidx, ew, cursor, pmeta);
    // after k_fill, cursor[a] == row end of atom a

    // ---- type-table h0, embed, filter tables ----
    k_embw<<<100, 128, 0, stream>>>(emb, lin1, embw);
    k_embed2<<<(N_ATOMS * H / 4) / 256, 256, 0, stream>>>(types, emb, embw, x, h);
    k_table<<<dim3(TBL / 128, NBLK), 256, 0, stream>>>(fw1, fb1, fw2, fb2, tab);

    for (int b = 0; b < NBLK; ++b) {
        k_edge4<<<N_ATOMS / 4, 256, 0, stream>>>(rstart, cursor, pmeta,
                                                 tab + (size_t)b * TBL * H, h, agg);
        if (b < NBLK - 1) {
            k_tail<true><<<N_ATOMS / 64, 256, 0, stream>>>(
                agg, lin2 + (size_t)b * H * H, lin2b + (size_t)b * H,
                linw + (size_t)b * H * H, linb + (size_t)b * H, x,
                lin1 + (size_t)(b + 1) * H * H, h);
        } else {
            k_tail<false><<<N_ATOMS / 64, 256, 0, stream>>>(
                agg, lin2 + (size_t)b * H * H, lin2b + (size_t)b * H,
                linw + (size_t)b * H * H, linb + (size_t)b * H, x,
                nullptr, nullptr);
        }
    }

    k_out<<<N_ATOMS / 64, 256, 0, stream>>>(x, o1w, o1b, o2w, o2b, out);
}

// Round 11
// 629.847 us; speedup vs baseline: 1.1822x; 1.0136x over previous
//
#include <hip/hip_runtime.h>
#include <hip/hip_fp16.h>
#include <math.h>

#define N_ATOMS 40000
#define E_EDGES 640000
#define H 128
#define RBF 64
#define NBLK 3
#define CUTF 5.0f
#define TBL 4096   // filter lookup table entries per block (1 MB fp16-pair -> L2-resident)

// stable fast tanh: exp-based, saturates correctly at +/-inf
__device__ __forceinline__ float fast_tanh(float x) {
    return 1.0f - 2.0f / (1.0f + __expf(2.0f * x));
}

// ---------------- embW = emb @ lin1[0]  (100 x 128) ----------------
__global__ __launch_bounds__(128) void k_embw(const float* __restrict__ emb,
                                              const float* __restrict__ lin1,
                                              float* __restrict__ embw) {
    const int t = blockIdx.x;
    const int c = threadIdx.x;
    float s = 0.0f;
#pragma unroll 8
    for (int k = 0; k < H; ++k) s = fmaf(emb[t * H + k], lin1[(size_t)k * H + c], s);
    embw[t * H + c] = s;
}

// ---------------- K0: x = emb[atom_types]; h = embW[atom_types] ----------------
__global__ __launch_bounds__(256) void k_embed2(const int* __restrict__ types,
                                                const float* __restrict__ emb,
                                                const float* __restrict__ embw,
                                                float* __restrict__ x,
                                                float* __restrict__ h) {
    int flat4 = blockIdx.x * 256 + threadIdx.x;  // over N*H/4
    int i = flat4 >> 5;
    int c4 = flat4 & 31;
    int t = types[i];
    ((float4*)(x + (size_t)i * H))[c4] = ((const float4*)(emb + (size_t)t * H))[c4];
    ((float4*)(h + (size_t)i * H))[c4] = ((const float4*)(embw + (size_t)t * H))[c4];
}

// ---------------- CSR build ----------------
__global__ __launch_bounds__(256) void k_count(const int* __restrict__ eidx,
                                               int* __restrict__ cnt) {
    int e = blockIdx.x * 256 + threadIdx.x;
    atomicAdd(&cnt[eidx[E_EDGES + e]], 1);
}

__global__ __launch_bounds__(1024) void k_scanA(const int* __restrict__ cnt,
                                                int* __restrict__ bsum) {
    __shared__ int ws[16];
    const int tid = threadIdx.x, lane = tid & 63, wid = tid >> 6;
    int idx = blockIdx.x * 1024 + tid;
    int v = (idx < N_ATOMS) ? cnt[idx] : 0;
#pragma unroll
    for (int off = 32; off; off >>= 1) v += __shfl_xor(v, off, 64);
    if (lane == 0) ws[wid] = v;
    __syncthreads();
    if (tid == 0) {
        int s = 0;
#pragma unroll
        for (int w = 0; w < 16; ++w) s += ws[w];
        bsum[blockIdx.x] = s;
    }
}

__global__ __launch_bounds__(64) void k_scanB(const int* __restrict__ bsum,
                                              int* __restrict__ boff) {
    const int lane = threadIdx.x;
    int v = (lane < 40) ? bsum[lane] : 0;
    int inc = v;
#pragma unroll
    for (int off = 1; off < 64; off <<= 1) {
        int t = __shfl_up(inc, off, 64);
        if (lane >= off) inc += t;
    }
    if (lane < 40) boff[lane] = inc - v;
}

__global__ __launch_bounds__(1024) void k_scanC(const int* __restrict__ cnt,
                                                const int* __restrict__ boff,
                                                int* __restrict__ cursor,
                                                int* __restrict__ rstart) {
    __shared__ int wsum[16];
    __shared__ int woff[16];
    const int tid = threadIdx.x, lane = tid & 63, wid = tid >> 6;
    int idx = blockIdx.x * 1024 + tid;
    int v = (idx < N_ATOMS) ? cnt[idx] : 0;
    int inc = v;
#pragma unroll
    for (int off = 1; off < 64; off <<= 1) {
        int t = __shfl_up(inc, off, 64);
        if (lane >= off) inc += t;
    }
    if (lane == 63) wsum[wid] = inc;
    __syncthreads();
    if (tid == 0) {
        int acc = 0;
#pragma unroll
        for (int w = 0; w < 16; ++w) { woff[w] = acc; acc += wsum[w]; }
    }
    __syncthreads();
    if (idx < N_ATOMS) {
        int ex = boff[blockIdx.x] + woff[wid] + inc - v;
        cursor[idx] = ex;
        rstart[idx] = ex;
    }
}

// fill: pmeta[pos] = {src, float_bits(u)}, u = d*(TBL-1)/CUT (dst-sorted)
__global__ __launch_bounds__(256) void k_fill(const int* __restrict__ eidx,
                                              const float* __restrict__ ew,
                                              int* __restrict__ cursor,
                                              int2* __restrict__ pmeta) {
    int e = blockIdx.x * 256 + threadIdx.x;
    int dd = eidx[E_EDGES + e];
    int pos = atomicAdd(&cursor[dd], 1);
    float u = ew[e] * ((float)(TBL - 1) / CUTF);
    pmeta[pos] = make_int2(eidx[e], __float_as_int(u));
}

// ---------------- K1: filter table build (fp16 interleaved pairs) ----------------
// tabI[m][c] = half2{ W(m)[c]*C(m), W(m+1)[c]*C(m+1) } so one row read gives both
// lerp endpoints. Entry m's .x written by row m, entry m-1's .y by row m.
__global__ __launch_bounds__(256, 2) void k_table(const float* __restrict__ fw1all,
                                                  const float* __restrict__ fb1all,
                                                  const float* __restrict__ fw2all,
                                                  const float* __restrict__ fb2all,
                                                  __half* __restrict__ tabH_all) {
    const int b = blockIdx.y;
    const float* fw1 = fw1all + (size_t)b * RBF * H;
    const float* fb1 = fb1all + (size_t)b * H;
    const float* fw2 = fw2all + (size_t)b * H * H;
    const float* fb2 = fb2all + (size_t)b * H;
    __half* tabH = tabH_all + (size_t)b * TBL * H * 2;

    __shared__ float tile[128 * 133];
    const int tid = threadIdx.x;
    const int mbase = blockIdx.x * 128;
    const float DSTEP = CUTF / (float)(TBL - 1);

    {
        const int e = tid & 127;
        const int k0 = (tid >> 7) * 32;
        const float d = (float)(mbase + e) * DSTEP;
        const float DELTA = CUTF / 63.0f;
        const float COEFF = -0.5f / (DELTA * DELTA);
#pragma unroll
        for (int k = k0; k < k0 + 32; ++k) {
            float diff = d - (float)k * DELTA;
            tile[e * 133 + k] = __expf(COEFF * diff * diff);
        }
    }
    __syncthreads();

    const int eg = tid >> 4, cg = tid & 15;
    const int e0 = eg * 8, c0 = cg * 8;

    float acc[8][8];
#pragma unroll
    for (int i = 0; i < 8; ++i)
#pragma unroll
        for (int j = 0; j < 8; ++j) acc[i][j] = 0.0f;

#pragma unroll 4
    for (int k = 0; k < RBF; ++k) {
        float a[8];
#pragma unroll
        for (int i = 0; i < 8; ++i) a[i] = tile[(e0 + i) * 133 + k];
        const float4 b0 = *(const float4*)(fw1 + (size_t)k * H + c0);
        const float4 b1 = *(const float4*)(fw1 + (size_t)k * H + c0 + 4);
        const float bb[8] = {b0.x, b0.y, b0.z, b0.w, b1.x, b1.y, b1.z, b1.w};
#pragma unroll
        for (int i = 0; i < 8; ++i)
#pragma unroll
            for (int j = 0; j < 8; ++j) acc[i][j] = fmaf(a[i], bb[j], acc[i][j]);
    }

    {
        const float4 q0 = *(const float4*)(fb1 + c0);
        const float4 q1 = *(const float4*)(fb1 + c0 + 4);
        const float bv[8] = {q0.x, q0.y, q0.z, q0.w, q1.x, q1.y, q1.z, q1.w};
#pragma unroll
        for (int i = 0; i < 8; ++i)
#pragma unroll
            for (int j = 0; j < 8; ++j) acc[i][j] = fast_tanh(acc[i][j] + bv[j]);
    }

    __syncthreads();
#pragma unroll
    for (int i = 0; i < 8; ++i)
#pragma unroll
        for (int j = 0; j < 8; ++j) tile[(e0 + i) * 133 + c0 + j] = acc[i][j];
    __syncthreads();

#pragma unroll
    for (int i = 0; i < 8; ++i)
#pragma unroll
        for (int j = 0; j < 8; ++j) acc[i][j] = 0.0f;

#pragma unroll 4
    for (int k = 0; k < H; ++k) {
        float a[8];
#pragma unroll
        for (int i = 0; i < 8; ++i) a[i] = tile[(e0 + i) * 133 + k];
        const float4 b0 = *(const float4*)(fw2 + (size_t)k * H + c0);
        const float4 b1 = *(const float4*)(fw2 + (size_t)k * H + c0 + 4);
        const float bb[8] = {b0.x, b0.y, b0.z, b0.w, b1.x, b1.y, b1.z, b1.w};
#pragma unroll
        for (int i = 0; i < 8; ++i)
#pragma unroll
            for (int j = 0; j < 8; ++j) acc[i][j] = fmaf(a[i], bb[j], acc[i][j]);
    }

    const float4 q0 = *(const float4*)(fb2 + c0);
    const float4 q1 = *(const float4*)(fb2 + c0 + 4);
    const float bv[8] = {q0.x, q0.y, q0.z, q0.w, q1.x, q1.y, q1.z, q1.w};

#pragma unroll
    for (int ei = 0; ei < 8; ++ei) {
        const int m = mbase + e0 + ei;
        const float d = (float)m * DSTEP;
        float c = 0.5f * (cosf(0.6283185307179586f * d) + 1.0f);
        c = (d < CUTF) ? c : 0.0f;
#pragma unroll
        for (int j = 0; j < 8; ++j) {
            const int col = c0 + j;
            const __half hv = __float2half_rn((acc[ei][j] + bv[j]) * c);
            tabH[((size_t)m * H + col) * 2] = hv;                      // entry m, .x
            if (m > 0)
                tabH[((size_t)(m - 1) * H + col) * 2 + 1] = hv;        // entry m-1, .y
        }
    }
}

// ---------------- LDS-staged weight panels for the tail GEMMs ----------------
// Panel = 32 rows x 128 cols of W (16 KB), loaded by global_load_lds width-16.
__device__ __forceinline__ void stage_panel(const float* __restrict__ Wg,
                                            float* wbuf, int tid) {
    const int w = tid >> 6, lane = tid & 63;
#pragma unroll
    for (int i = 0; i < 4; ++i) {
        const float* g = Wg + ((w << 2) + i) * 256 + (lane << 2);
        float* l = wbuf + ((w << 2) + i) * 256;   // uniform across the wave
        __builtin_amdgcn_global_load_lds((const __attribute__((address_space(1))) void*)g,
                                         (__attribute__((address_space(3))) void*)l,
                                         16, 0, 0);
    }
}

// acc += A(64x128 LDS, stride 132) @ W(128x128 global via LDS panels).
// Split-column map: thread covers cols [cA,cA+4) and [cB,cB+4) (cB = cA+64)
// -> W ds_read_b128 is 256B/16-lane contiguous = 2-way bank alias = free.
__device__ __forceinline__ void gemm_lds(const float* __restrict__ at,
                                         const float* __restrict__ Wg,
                                         float* __restrict__ wb0,
                                         float* __restrict__ wb1,
                                         int tid, int r0, int cA, int cB,
                                         float acc[4][8]) {
#pragma unroll
    for (int i = 0; i < 4; ++i)
#pragma unroll
        for (int j = 0; j < 8; ++j) acc[i][j] = 0.0f;

    stage_panel(Wg, wb0, tid);
    __syncthreads();   // panel 0 resident (also covers at[] staging before 1st call)

#pragma unroll
    for (int p = 0; p < 4; ++p) {
        float* cur = (p & 1) ? wb1 : wb0;
        float* nxt = (p & 1) ? wb0 : wb1;
        if (p < 3) stage_panel(Wg + (size_t)(p + 1) * 32 * H, nxt, tid);
        const int kb = p * 32;
#pragma unroll
        for (int k4 = 0; k4 < 32; k4 += 4) {
            float4 av[4];
#pragma unroll
            for (int i = 0; i < 4; ++i)
                av[i] = *(const float4*)&at[(r0 + i) * 132 + kb + k4];
            const float* avf = (const float*)av;
#pragma unroll
            for (int kk = 0; kk < 4; ++kk) {
                const float4 w0 = *(const float4*)&cur[(k4 + kk) * H + cA];
                const float4 w1 = *(const float4*)&cur[(k4 + kk) * H + cB];
                const float wv[8] = {w0.x, w0.y, w0.z, w0.w, w1.x, w1.y, w1.z, w1.w};
#pragma unroll
                for (int i = 0; i < 4; ++i) {
                    const float a = avf[i * 4 + kk];
#pragma unroll
                    for (int j = 0; j < 8; ++j) acc[i][j] = fmaf(a, wv[j], acc[i][j]);
                }
            }
        }
        __syncthreads();   // all reads of cur done; next panel's loads landed
    }
}

// ---------------- fused tail (256 thr, 64-atom tile, split-col 4x8 micro):
// x += tanh(agg@lin2+b2)@linw + bl ; optionally h = x_new@lin1_next
template <bool MAKE_H>
__global__ __launch_bounds__(256) void k_tail(const float* __restrict__ agg,
                                              const float* __restrict__ lin2,
                                              const float* __restrict__ b2,
                                              const float* __restrict__ linw,
                                              const float* __restrict__ bl,
                                              float* __restrict__ x,
                                              const float* __restrict__ lin1n,
                                              float* __restrict__ hout) {
    __shared__ float at[64 * 132];
    __shared__ float wpan0[32 * H];
    __shared__ float wpan1[32 * H];
    const int tid = threadIdx.x;
    const int abase = blockIdx.x * 64;

    // stage agg tile [64][128] -> LDS (stride 132)
#pragma unroll
    for (int i = 0; i < 8; ++i) {
        int flat4 = tid + 256 * i;
        int r = flat4 >> 5, k4 = flat4 & 31;
        float4 v = ((const float4*)(agg + (size_t)(abase + r) * H))[k4];
        *(float4*)&at[r * 132 + k4 * 4] = v;
    }
    // gemm_lds prologue barrier covers visibility

    const int eg = tid >> 4, cg = tid & 15;   // 16 x 16 thread grid
    const int r0 = eg * 4;
    const int cA = cg * 4, cB = 64 + cg * 4;  // split column groups

    float acc[4][8];

    // stage 1: tanh(agg @ lin2 + b2)
    gemm_lds(at, lin2, wpan0, wpan1, tid, r0, cA, cB, acc);
    {
        const float4 q0 = *(const float4*)(b2 + cA);
        const float4 q1 = *(const float4*)(b2 + cB);
        const float bv[8] = {q0.x, q0.y, q0.z, q0.w, q1.x, q1.y, q1.z, q1.w};
#pragma unroll
        for (int i = 0; i < 4; ++i)
#pragma unroll
            for (int j = 0; j < 8; ++j) acc[i][j] = fast_tanh(acc[i][j] + bv[j]);
    }
    // write t tile (float4 per col-group; 2-way alias = free)
#pragma unroll
    for (int i = 0; i < 4; ++i) {
        *(float4*)&at[(r0 + i) * 132 + cA] = make_float4(acc[i][0], acc[i][1], acc[i][2], acc[i][3]);
        *(float4*)&at[(r0 + i) * 132 + cB] = make_float4(acc[i][4], acc[i][5], acc[i][6], acc[i][7]);
    }
    __syncthreads();

    // stage 2: t @ linw ; x += . + bl
    gemm_lds(at, linw, wpan0, wpan1, tid, r0, cA, cB, acc);
    {
        const float4 q0 = *(const float4*)(bl + cA);
        const float4 q1 = *(const float4*)(bl + cB);
        const float bv[8] = {q0.x, q0.y, q0.z, q0.w, q1.x, q1.y, q1.z, q1.w};
#pragma unroll
        for (int ei = 0; ei < 4; ++ei) {
            const int row = abase + r0 + ei;
            float* opA = x + (size_t)row * H + cA;
            float* opB = x + (size_t)row * H + cB;
            float4 x0 = *(const float4*)(opA);
            float4 x1 = *(const float4*)(opB);
            float xn[8] = {x0.x + acc[ei][0] + bv[0], x0.y + acc[ei][1] + bv[1],
                           x0.z + acc[ei][2] + bv[2], x0.w + acc[ei][3] + bv[3],
                           x1.x + acc[ei][4] + bv[4], x1.y + acc[ei][5] + bv[5],
                           x1.z + acc[ei][6] + bv[6], x1.w + acc[ei][7] + bv[7]};
            *(float4*)(opA) = make_float4(xn[0], xn[1], xn[2], xn[3]);
            *(float4*)(opB) = make_float4(xn[4], xn[5], xn[6], xn[7]);
            if (MAKE_H) {
                *(float4*)&at[(r0 + ei) * 132 + cA] = make_float4(xn[0], xn[1], xn[2], xn[3]);
                *(float4*)&at[(r0 + ei) * 132 + cB] = make_float4(xn[4], xn[5], xn[6], xn[7]);
            }
        }
    }

    if (MAKE_H) {
        __syncthreads();
        // stage 3: h = x_new @ lin1_next
        gemm_lds(at, lin1n, wpan0, wpan1, tid, r0, cA, cB, acc);
#pragma unroll
        for (int ei = 0; ei < 4; ++ei) {
            const int row = abase + r0 + ei;
            *(float4*)(hout + (size_t)row * H + cA) =
                make_float4(acc[ei][0], acc[ei][1], acc[ei][2], acc[ei][3]);
            *(float4*)(hout + (size_t)row * H + cB) =
                make_float4(acc[ei][4], acc[ei][5], acc[ei][6], acc[ei][7]);
        }
    }
}

// ---------------- K2: atom-centric gather, fp16 pair-table lerp ----------------
__global__ __launch_bounds__(256) void k_edge5(const int* __restrict__ rstart,
                                               const int* __restrict__ rend,
                                               const int2* __restrict__ pmeta,
                                               const __half2* __restrict__ tabI,
                                               const float* __restrict__ h,
                                               float* __restrict__ agg) {
    const int wave = threadIdx.x >> 6;
    const int lane = threadIdx.x & 63;
    const int a = blockIdx.x * 4 + wave;
    const int col0 = lane * 2;

    const int s = rstart[a];
    const int n = rend[a] - s;

    float s0 = 0.0f, s1 = 0.0f;
    if (n <= 64) {
        int2 meta = make_int2(0, 0);
        if (lane < n) meta = pmeta[s + lane];
#pragma unroll 2
        for (int e = 0; e < n; ++e) {
            const int src = __shfl(meta.x, e, 64);
            const float u = __int_as_float(__shfl(meta.y, e, 64));
            int i0 = (int)u;
            i0 = (i0 > TBL - 2) ? (TBL - 2) : i0;
            const float f = u - (float)i0;
            const uint2 pr = *(const uint2*)(tabI + (size_t)i0 * H + col0);  // 8B: 2 pairs
            const __half2* ph = (const __half2*)&pr;
            const float2 p0 = __half22float2(ph[0]);
            const float2 p1 = __half22float2(ph[1]);
            const float2 hv = *(const float2*)(h + (size_t)src * H + col0);
            s0 = fmaf(fmaf(f, p0.y - p0.x, p0.x), hv.x, s0);
            s1 = fmaf(fmaf(f, p1.y - p1.x, p1.x), hv.y, s1);
        }
    } else {
        for (int e = s; e < s + n; ++e) {
            const int2 m = pmeta[e];
            const float u = __int_as_float(m.y);
            int i0 = (int)u;
            i0 = (i0 > TBL - 2) ? (TBL - 2) : i0;
            const float f = u - (float)i0;
            const uint2 pr = *(const uint2*)(tabI + (size_t)i0 * H + col0);
            const __half2* ph = (const __half2*)&pr;
            const float2 p0 = __half22float2(ph[0]);
            const float2 p1 = __half22float2(ph[1]);
            const float2 hv = *(const float2*)(h + (size_t)m.x * H + col0);
            s0 = fmaf(fmaf(f, p0.y - p0.x, p0.x), hv.x, s0);
            s1 = fmaf(fmaf(f, p1.y - p1.x, p1.x), hv.y, s1);
        }
    }
    *(float2*)(agg + (size_t)a * H + col0) = make_float2(s0, s1);
}

// ---------------- K5: energy, 64 atoms x 64 cols per 256-thread block ----------------
__global__ __launch_bounds__(256) void k_out(const float* __restrict__ x,
                                             const float* __restrict__ o1w,
                                             const float* __restrict__ o1b,
                                             const float* __restrict__ o2w,
                                             const float* __restrict__ o2b,
                                             float* __restrict__ out) {
    __shared__ float xs[64 * 132];
    const int tid = threadIdx.x;
    const int abase = blockIdx.x * 64;

#pragma unroll
    for (int i = 0; i < 8; ++i) {
        int flat4 = tid + 256 * i;
        int r = flat4 >> 5, k4 = flat4 & 31;
        float4 v = ((const float4*)(x + (size_t)(abase + r) * H))[k4];
        float* dp = &xs[r * 132 + k4 * 4];
        dp[0] = v.x; dp[1] = v.y; dp[2] = v.z; dp[3] = v.w;
    }
    __syncthreads();

    const int eg = tid >> 4, cg = tid & 15;
    const int r0 = eg * 4, c0 = cg * 4;

    float acc[4][4];
#pragma unroll
    for (int i = 0; i < 4; ++i)
#pragma unroll
        for (int j = 0; j < 4; ++j) acc[i][j] = 0.0f;

#pragma unroll 4
    for (int k = 0; k < H; ++k) {
        float a[4];
#pragma unroll
        for (int i = 0; i < 4; ++i) a[i] = xs[(r0 + i) * 132 + k];
        const float4 b = *(const float4*)(o1w + (size_t)k * 64 + c0);
        const float bb[4] = {b.x, b.y, b.z, b.w};
#pragma unroll
        for (int i = 0; i < 4; ++i)
#pragma unroll
            for (int j = 0; j < 4; ++j) acc[i][j] = fmaf(a[i], bb[j], acc[i][j]);
    }

    const float4 ob = *(const float4*)(o1b + c0);
    const float4 ow = *(const float4*)(o2w + c0);
    const float obv[4] = {ob.x, ob.y, ob.z, ob.w};
    const float owv[4] = {ow.x, ow.y, ow.z, ow.w};
    float p[4];
#pragma unroll
    for (int i = 0; i < 4; ++i) {
        float s = 0.0f;
#pragma unroll
        for (int j = 0; j < 4; ++j) s = fmaf(fast_tanh(acc[i][j] + obv[j]), owv[j], s);
        p[i] = s;
    }
#pragma unroll
    for (int off = 1; off < 16; off <<= 1) {
#pragma unroll
        for (int i = 0; i < 4; ++i) p[i] += __shfl_xor(p[i], off, 64);
    }
    if (cg == 0) {
        const float b2 = o2b[0];
#pragma unroll
        for (int i = 0; i < 4; ++i) out[abase + r0 + i] = p[i] + b2;
    }
}

extern "C" void kernel_launch(void* const* d_in, const int* in_sizes, int n_in,
                              void* d_out, int out_size, void* d_ws, size_t ws_size,
                              hipStream_t stream) {
    const int*   types = (const int*)d_in[0];
    const int*   eidx  = (const int*)d_in[1];
    const float* ew    = (const float*)d_in[2];
    const float* emb   = (const float*)d_in[3];
    const float* lin1  = (const float*)d_in[4];
    const float* fw1   = (const float*)d_in[5];
    const float* fb1   = (const float*)d_in[6];
    const float* fw2   = (const float*)d_in[7];
    const float* fb2   = (const float*)d_in[8];
    const float* lin2  = (const float*)d_in[9];
    const float* lin2b = (const float*)d_in[10];
    const float* linw  = (const float*)d_in[11];
    const float* linb  = (const float*)d_in[12];
    const float* o1w   = (const float*)d_in[13];
    const float* o1b   = (const float*)d_in[14];
    const float* o2w   = (const float*)d_in[15];
    const float* o2b   = (const float*)d_in[16];
    float* out = (float*)d_out;

    // ws carve (tab as half2 = 4B per entry -> counts as one float each)
    float* x      = (float*)d_ws;                            // N*H
    float* h      = x + (size_t)N_ATOMS * H;                 // N*H
    float* agg    = h + (size_t)N_ATOMS * H;                 // N*H
    float* tab    = agg + (size_t)N_ATOMS * H;               // NBLK*TBL*H (half2 units)
    float* embw   = tab + (size_t)NBLK * TBL * H;            // 100*H
    int*   cnt    = (int*)(embw + 100 * H);                  // N
    int*   cursor = cnt + N_ATOMS;                           // N
    int*   rstart = cursor + N_ATOMS;                        // N
    int*   bsum   = rstart + N_ATOMS;                        // 40 (pad 64)
    int*   boff   = bsum + 64;                               // 40 (pad 64)
    int2*  pmeta  = (int2*)(boff + 64);                      // E

    // ---- CSR build ----
    hipMemsetAsync(cnt, 0, N_ATOMS * sizeof(int), stream);
    k_count<<<E_EDGES / 256, 256, 0, stream>>>(eidx, cnt);
    k_scanA<<<40, 1024, 0, stream>>>(cnt, bsum);
    k_scanB<<<1, 64, 0, stream>>>(bsum, boff);
    k_scanC<<<40, 1024, 0, stream>>>(cnt, boff, cursor, rstart);
    k_fill<<<E_EDGES / 256, 256, 0, stream>>>(eidx, ew, cursor, pmeta);
    // after k_fill, cursor[a] == row end of atom a

    // ---- type-table h0, embed, filter tables ----
    k_embw<<<100, 128, 0, stream>>>(emb, lin1, embw);
    k_embed2<<<(N_ATOMS * H / 4) / 256, 256, 0, stream>>>(types, emb, embw, x, h);
    k_table<<<dim3(TBL / 128, NBLK), 256, 0, stream>>>(fw1, fb1, fw2, fb2, (__half*)tab);

    for (int b = 0; b < NBLK; ++b) {
        k_edge5<<<N_ATOMS / 4, 256, 0, stream>>>(rstart, cursor, pmeta,
                                                 (const __half2*)tab + (size_t)b * TBL * H,
                                                 h, agg);
        if (b < NBLK - 1) {
            k_tail<true><<<N_ATOMS / 64, 256, 0, stream>>>(
                agg, lin2 + (size_t)b * H * H, lin2b + (size_t)b * H,
                linw + (size_t)b * H * H, linb + (size_t)b * H, x,
                lin1 + (size_t)(b + 1) * H * H, h);
        } else {
            k_tail<false><<<N_ATOMS / 64, 256, 0, stream>>>(
                agg, lin2 + (size_t)b * H * H, lin2b + (size_t)b * H,
                linw + (size_t)b * H * H, linb + (size_t)b * H, x,
                nullptr, nullptr);
        }
    }

    k_out<<<N_ATOMS / 64, 256, 0, stream>>>(x, o1w, o1b, o2w, o2b, out);
}

// Round 14
// 616.986 us; speedup vs baseline: 1.2068x; 1.0208x over previous
//
#include <hip/hip_runtime.h>
#include <hip/hip_fp16.h>
#include <math.h>

#define N_ATOMS 40000
#define E_EDGES 640000
#define H 128
#define RBF 64
#define NBLK 3
#define CUTF 5.0f
#define TBL 4096   // filter lookup table entries per block (1 MB fp16-pair -> L2-resident)

// stable fast tanh: exp-based, saturates correctly at +/-inf
__device__ __forceinline__ float fast_tanh(float x) {
    return 1.0f - 2.0f / (1.0f + __expf(2.0f * x));
}

// ---------------- embW = emb @ lin1[0]  (100 x 128) ----------------
__global__ __launch_bounds__(128) void k_embw(const float* __restrict__ emb,
                                              const float* __restrict__ lin1,
                                              float* __restrict__ embw) {
    const int t = blockIdx.x;
    const int c = threadIdx.x;
    float s = 0.0f;
#pragma unroll 8
    for (int k = 0; k < H; ++k) s = fmaf(emb[t * H + k], lin1[(size_t)k * H + c], s);
    embw[t * H + c] = s;
}

// ---------------- K0: x = emb[atom_types]; h = embW[atom_types] ----------------
__global__ __launch_bounds__(256) void k_embed2(const int* __restrict__ types,
                                                const float* __restrict__ emb,
                                                const float* __restrict__ embw,
                                                float* __restrict__ x,
                                                float* __restrict__ h) {
    int flat4 = blockIdx.x * 256 + threadIdx.x;  // over N*H/4
    int i = flat4 >> 5;
    int c4 = flat4 & 31;
    int t = types[i];
    ((float4*)(x + (size_t)i * H))[c4] = ((const float4*)(emb + (size_t)t * H))[c4];
    ((float4*)(h + (size_t)i * H))[c4] = ((const float4*)(embw + (size_t)t * H))[c4];
}

// ---------------- CSR build ----------------
__global__ __launch_bounds__(256) void k_count(const int* __restrict__ eidx,
                                               int* __restrict__ cnt) {
    int e = blockIdx.x * 256 + threadIdx.x;
    atomicAdd(&cnt[eidx[E_EDGES + e]], 1);
}

__global__ __launch_bounds__(1024) void k_scanA(const int* __restrict__ cnt,
                                                int* __restrict__ bsum) {
    __shared__ int ws[16];
    const int tid = threadIdx.x, lane = tid & 63, wid = tid >> 6;
    int idx = blockIdx.x * 1024 + tid;
    int v = (idx < N_ATOMS) ? cnt[idx] : 0;
#pragma unroll
    for (int off = 32; off; off >>= 1) v += __shfl_xor(v, off, 64);
    if (lane == 0) ws[wid] = v;
    __syncthreads();
    if (tid == 0) {
        int s = 0;
#pragma unroll
        for (int w = 0; w < 16; ++w) s += ws[w];
        bsum[blockIdx.x] = s;
    }
}

__global__ __launch_bounds__(64) void k_scanB(const int* __restrict__ bsum,
                                              int* __restrict__ boff) {
    const int lane = threadIdx.x;
    int v = (lane < 40) ? bsum[lane] : 0;
    int inc = v;
#pragma unroll
    for (int off = 1; off < 64; off <<= 1) {
        int t = __shfl_up(inc, off, 64);
        if (lane >= off) inc += t;
    }
    if (lane < 40) boff[lane] = inc - v;
}

__global__ __launch_bounds__(1024) void k_scanC(const int* __restrict__ cnt,
                                                const int* __restrict__ boff,
                                                int* __restrict__ cursor,
                                                int* __restrict__ rstart) {
    __shared__ int wsum[16];
    __shared__ int woff[16];
    const int tid = threadIdx.x, lane = tid & 63, wid = tid >> 6;
    int idx = blockIdx.x * 1024 + tid;
    int v = (idx < N_ATOMS) ? cnt[idx] : 0;
    int inc = v;
#pragma unroll
    for (int off = 1; off < 64; off <<= 1) {
        int t = __shfl_up(inc, off, 64);
        if (lane >= off) inc += t;
    }
    if (lane == 63) wsum[wid] = inc;
    __syncthreads();
    if (tid == 0) {
        int acc = 0;
#pragma unroll
        for (int w = 0; w < 16; ++w) { woff[w] = acc; acc += wsum[w]; }
    }
    __syncthreads();
    if (idx < N_ATOMS) {
        int ex = boff[blockIdx.x] + woff[wid] + inc - v;
        cursor[idx] = ex;
        rstart[idx] = ex;
    }
}

// fill: pmeta[pos] = {src, float_bits(u)}, u = d*(TBL-1)/CUT (dst-sorted)
__global__ __launch_bounds__(256) void k_fill(const int* __restrict__ eidx,
                                              const float* __restrict__ ew,
                                              int* __restrict__ cursor,
                                              int2* __restrict__ pmeta) {
    int e = blockIdx.x * 256 + threadIdx.x;
    int dd = eidx[E_EDGES + e];
    int pos = atomicAdd(&cursor[dd], 1);
    float u = ew[e] * ((float)(TBL - 1) / CUTF);
    pmeta[pos] = make_int2(eidx[e], __float_as_int(u));
}

// ---------------- K1: filter table build (fp16 interleaved pairs) ----------------
// tabI[m][c] = half2{ W(m)[c]*C(m), W(m+1)[c]*C(m+1) } so one row read gives both
// lerp endpoints. Entry m's .x written by row m, entry m-1's .y by row m.
__global__ __launch_bounds__(256, 2) void k_table(const float* __restrict__ fw1all,
                                                  const float* __restrict__ fb1all,
                                                  const float* __restrict__ fw2all,
                                                  const float* __restrict__ fb2all,
                                                  __half* __restrict__ tabH_all) {
    const int b = blockIdx.y;
    const float* fw1 = fw1all + (size_t)b * RBF * H;
    const float* fb1 = fb1all + (size_t)b * H;
    const float* fw2 = fw2all + (size_t)b * H * H;
    const float* fb2 = fb2all + (size_t)b * H;
    __half* tabH = tabH_all + (size_t)b * TBL * H * 2;

    __shared__ float tile[128 * 133];
    const int tid = threadIdx.x;
    const int mbase = blockIdx.x * 128;
    const float DSTEP = CUTF / (float)(TBL - 1);

    {
        const int e = tid & 127;
        const int k0 = (tid >> 7) * 32;
        const float d = (float)(mbase + e) * DSTEP;
        const float DELTA = CUTF / 63.0f;
        const float COEFF = -0.5f / (DELTA * DELTA);
#pragma unroll
        for (int k = k0; k < k0 + 32; ++k) {
            float diff = d - (float)k * DELTA;
            tile[e * 133 + k] = __expf(COEFF * diff * diff);
        }
    }
    __syncthreads();

    const int eg = tid >> 4, cg = tid & 15;
    const int e0 = eg * 8, c0 = cg * 8;

    float acc[8][8];
#pragma unroll
    for (int i = 0; i < 8; ++i)
#pragma unroll
        for (int j = 0; j < 8; ++j) acc[i][j] = 0.0f;

#pragma unroll 4
    for (int k = 0; k < RBF; ++k) {
        float a[8];
#pragma unroll
        for (int i = 0; i < 8; ++i) a[i] = tile[(e0 + i) * 133 + k];
        const float4 b0 = *(const float4*)(fw1 + (size_t)k * H + c0);
        const float4 b1 = *(const float4*)(fw1 + (size_t)k * H + c0 + 4);
        const float bb[8] = {b0.x, b0.y, b0.z, b0.w, b1.x, b1.y, b1.z, b1.w};
#pragma unroll
        for (int i = 0; i < 8; ++i)
#pragma unroll
            for (int j = 0; j < 8; ++j) acc[i][j] = fmaf(a[i], bb[j], acc[i][j]);
    }

    {
        const float4 q0 = *(const float4*)(fb1 + c0);
        const float4 q1 = *(const float4*)(fb1 + c0 + 4);
        const float bv[8] = {q0.x, q0.y, q0.z, q0.w, q1.x, q1.y, q1.z, q1.w};
#pragma unroll
        for (int i = 0; i < 8; ++i)
#pragma unroll
            for (int j = 0; j < 8; ++j) acc[i][j] = fast_tanh(acc[i][j] + bv[j]);
    }

    __syncthreads();
#pragma unroll
    for (int i = 0; i < 8; ++i)
#pragma unroll
        for (int j = 0; j < 8; ++j) tile[(e0 + i) * 133 + c0 + j] = acc[i][j];
    __syncthreads();

#pragma unroll
    for (int i = 0; i < 8; ++i)
#pragma unroll
        for (int j = 0; j < 8; ++j) acc[i][j] = 0.0f;

#pragma unroll 4
    for (int k = 0; k < H; ++k) {
        float a[8];
#pragma unroll
        for (int i = 0; i < 8; ++i) a[i] = tile[(e0 + i) * 133 + k];
        const float4 b0 = *(const float4*)(fw2 + (size_t)k * H + c0);
        const float4 b1 = *(const float4*)(fw2 + (size_t)k * H + c0 + 4);
        const float bb[8] = {b0.x, b0.y, b0.z, b0.w, b1.x, b1.y, b1.z, b1.w};
#pragma unroll
        for (int i = 0; i < 8; ++i)
#pragma unroll
            for (int j = 0; j < 8; ++j) acc[i][j] = fmaf(a[i], bb[j], acc[i][j]);
    }

    const float4 q0 = *(const float4*)(fb2 + c0);
    const float4 q1 = *(const float4*)(fb2 + c0 + 4);
    const float bv[8] = {q0.x, q0.y, q0.z, q0.w, q1.x, q1.y, q1.z, q1.w};

#pragma unroll
    for (int ei = 0; ei < 8; ++ei) {
        const int m = mbase + e0 + ei;
        const float d = (float)m * DSTEP;
        float c = 0.5f * (cosf(0.6283185307179586f * d) + 1.0f);
        c = (d < CUTF) ? c : 0.0f;
#pragma unroll
        for (int j = 0; j < 8; ++j) {
            const int col = c0 + j;
            const __half hv = __float2half_rn((acc[ei][j] + bv[j]) * c);
            tabH[((size_t)m * H + col) * 2] = hv;                      // entry m, .x
            if (m > 0)
                tabH[((size_t)(m - 1) * H + col) * 2 + 1] = hv;        // entry m-1, .y
        }
    }
}

// ---------------- LDS-staged weight panels for the tail GEMMs ----------------
// Panel = 16 rows x 128 cols of W (8 KB), loaded by global_load_lds width-16.
// 16-row panels keep total LDS at 50 KB -> 3 blocks/CU -> whole 625-block grid
// co-resident (no straggler round; 3 blocks overlap each barrier).
__device__ __forceinline__ void stage_panel(const float* __restrict__ Wg,
                                            float* wbuf, int tid) {
    const int w = tid >> 6, lane = tid & 63;
#pragma unroll
    for (int i = 0; i < 2; ++i) {
        const float* g = Wg + ((w * 2 + i) * 256) + (lane << 2);
        float* l = wbuf + (w * 2 + i) * 256;   // uniform across the wave
        __builtin_amdgcn_global_load_lds((const __attribute__((address_space(1))) void*)g,
                                         (__attribute__((address_space(3))) void*)l,
                                         16, 0, 0);
    }
}

// acc += A(64x128 LDS, stride 132) @ W(128x128 global via 8x 16-row LDS panels).
// Split-column map: thread covers cols [cA,cA+4) and [cB,cB+4) (cB = cA+64)
// -> W ds_read_b128 is 256B/16-lane contiguous = 2-way bank alias = free.
// p-loop unrolled by 2 (NOT fully): keeps cur/nxt parity static for the
// double-buffer while holding compile-time code size down (R12/R13 full-unroll
// builds never came back from the container -- suspected compile blowup).
__device__ __forceinline__ void gemm_lds(const float* __restrict__ at,
                                         const float* __restrict__ Wg,
                                         float* __restrict__ wb0,
                                         float* __restrict__ wb1,
                                         int tid, int r0, int cA, int cB,
                                         float acc[4][8]) {
#pragma unroll
    for (int i = 0; i < 4; ++i)
#pragma unroll
        for (int j = 0; j < 8; ++j) acc[i][j] = 0.0f;

    stage_panel(Wg, wb0, tid);
    __syncthreads();   // panel 0 resident (also covers at[] staging before 1st call)

#pragma unroll 2
    for (int p = 0; p < 8; ++p) {
        float* cur = (p & 1) ? wb1 : wb0;
        float* nxt = (p & 1) ? wb0 : wb1;
        if (p < 7) stage_panel(Wg + (size_t)(p + 1) * 16 * H, nxt, tid);
        const int kb = p * 16;
#pragma unroll
        for (int k4 = 0; k4 < 16; k4 += 4) {
            float4 av[4];
#pragma unroll
            for (int i = 0; i < 4; ++i)
                av[i] = *(const float4*)&at[(r0 + i) * 132 + kb + k4];
            const float* avf = (const float*)av;
#pragma unroll
            for (int kk = 0; kk < 4; ++kk) {
                const float4 w0 = *(const float4*)&cur[(k4 + kk) * H + cA];
                const float4 w1 = *(const float4*)&cur[(k4 + kk) * H + cB];
                const float wv[8] = {w0.x, w0.y, w0.z, w0.w, w1.x, w1.y, w1.z, w1.w};
#pragma unroll
                for (int i = 0; i < 4; ++i) {
                    const float a = avf[i * 4 + kk];
#pragma unroll
                    for (int j = 0; j < 8; ++j) acc[i][j] = fmaf(a, wv[j], acc[i][j]);
                }
            }
        }
        __syncthreads();   // all reads of cur done; next panel's loads landed
    }
}

// ---------------- fused tail (256 thr, 64-atom tile, split-col 4x8 micro):
// x += tanh(agg@lin2+b2)@linw + bl ; optionally h = x_new@lin1_next
template <bool MAKE_H>
__global__ __launch_bounds__(256) void k_tail(const float* __restrict__ agg,
                                              const float* __restrict__ lin2,
                                              const float* __restrict__ b2,
                                              const float* __restrict__ linw,
                                              const float* __restrict__ bl,
                                              float* __restrict__ x,
                                              const float* __restrict__ lin1n,
                                              float* __restrict__ hout) {
    __shared__ float at[64 * 132];
    __shared__ float wpan0[16 * H];
    __shared__ float wpan1[16 * H];
    const int tid = threadIdx.x;
    const int abase = blockIdx.x * 64;

    // stage agg tile [64][128] -> LDS (stride 132)
#pragma unroll
    for (int i = 0; i < 8; ++i) {
        int flat4 = tid + 256 * i;
        int r = flat4 >> 5, k4 = flat4 & 31;
        float4 v = ((const float4*)(agg + (size_t)(abase + r) * H))[k4];
        *(float4*)&at[r * 132 + k4 * 4] = v;
    }
    // gemm_lds prologue barrier covers visibility

    const int eg = tid >> 4, cg = tid & 15;   // 16 x 16 thread grid
    const int r0 = eg * 4;
    const int cA = cg * 4, cB = 64 + cg * 4;  // split column groups

    float acc[4][8];

    // stage 1: tanh(agg @ lin2 + b2)
    gemm_lds(at, lin2, wpan0, wpan1, tid, r0, cA, cB, acc);
    {
        const float4 q0 = *(const float4*)(b2 + cA);
        const float4 q1 = *(const float4*)(b2 + cB);
        const float bv[8] = {q0.x, q0.y, q0.z, q0.w, q1.x, q1.y, q1.z, q1.w};
#pragma unroll
        for (int i = 0; i < 4; ++i)
#pragma unroll
            for (int j = 0; j < 8; ++j) acc[i][j] = fast_tanh(acc[i][j] + bv[j]);
    }
    // write t tile (float4 per col-group; 2-way alias = free)
#pragma unroll
    for (int i = 0; i < 4; ++i) {
        *(float4*)&at[(r0 + i) * 132 + cA] = make_float4(acc[i][0], acc[i][1], acc[i][2], acc[i][3]);
        *(float4*)&at[(r0 + i) * 132 + cB] = make_float4(acc[i][4], acc[i][5], acc[i][6], acc[i][7]);
    }
    __syncthreads();

    // stage 2: t @ linw ; x += . + bl
    gemm_lds(at, linw, wpan0, wpan1, tid, r0, cA, cB, acc);
    {
        const float4 q0 = *(const float4*)(bl + cA);
        const float4 q1 = *(const float4*)(bl + cB);
        const float bv[8] = {q0.x, q0.y, q0.z, q0.w, q1.x, q1.y, q1.z, q1.w};
#pragma unroll
        for (int ei = 0; ei < 4; ++ei) {
            const int row = abase + r0 + ei;
            float* opA = x + (size_t)row * H + cA;
            float* opB = x + (size_t)row * H + cB;
            float4 x0 = *(const float4*)(opA);
            float4 x1 = *(const float4*)(opB);
            float xn[8] = {x0.x + acc[ei][0] + bv[0], x0.y + acc[ei][1] + bv[1],
                           x0.z + acc[ei][2] + bv[2], x0.w + acc[ei][3] + bv[3],
                           x1.x + acc[ei][4] + bv[4], x1.y + acc[ei][5] + bv[5],
                           x1.z + acc[ei][6] + bv[6], x1.w + acc[ei][7] + bv[7]};
            *(float4*)(opA) = make_float4(xn[0], xn[1], xn[2], xn[3]);
            *(float4*)(opB) = make_float4(xn[4], xn[5], xn[6], xn[7]);
            if (MAKE_H) {
                *(float4*)&at[(r0 + ei) * 132 + cA] = make_float4(xn[0], xn[1], xn[2], xn[3]);
                *(float4*)&at[(r0 + ei) * 132 + cB] = make_float4(xn[4], xn[5], xn[6], xn[7]);
            }
        }
    }

    if (MAKE_H) {
        __syncthreads();
        // stage 3: h = x_new @ lin1_next
        gemm_lds(at, lin1n, wpan0, wpan1, tid, r0, cA, cB, acc);
#pragma unroll
        for (int ei = 0; ei < 4; ++ei) {
            const int row = abase + r0 + ei;
            *(float4*)(hout + (size_t)row * H + cA) =
                make_float4(acc[ei][0], acc[ei][1], acc[ei][2], acc[ei][3]);
            *(float4*)(hout + (size_t)row * H + cB) =
                make_float4(acc[ei][4], acc[ei][5], acc[ei][6], acc[ei][7]);
        }
    }
}

// ---------------- K2: atom-centric gather, fp16 pair-table lerp ----------------
__global__ __launch_bounds__(256) void k_edge5(const int* __restrict__ rstart,
                                               const int* __restrict__ rend,
                                               const int2* __restrict__ pmeta,
                                               const __half2* __restrict__ tabI,
                                               const float* __restrict__ h,
                                               float* __restrict__ agg) {
    const int wave = threadIdx.x >> 6;
    const int lane = threadIdx.x & 63;
    const int a = blockIdx.x * 4 + wave;
    const int col0 = lane * 2;

    const int s = rstart[a];
    const int n = rend[a] - s;

    float s0 = 0.0f, s1 = 0.0f;
    if (n <= 64) {
        int2 meta = make_int2(0, 0);
        if (lane < n) meta = pmeta[s + lane];
#pragma unroll 2
        for (int e = 0; e < n; ++e) {
            const int src = __shfl(meta.x, e, 64);
            const float u = __int_as_float(__shfl(meta.y, e, 64));
            int i0 = (int)u;
            i0 = (i0 > TBL - 2) ? (TBL - 2) : i0;
            const float f = u - (float)i0;
            const uint2 pr = *(const uint2*)(tabI + (size_t)i0 * H + col0);  // 8B: 2 pairs
            const __half2* ph = (const __half2*)&pr;
            const float2 p0 = __half22float2(ph[0]);
            const float2 p1 = __half22float2(ph[1]);
            const float2 hv = *(const float2*)(h + (size_t)src * H + col0);
            s0 = fmaf(fmaf(f, p0.y - p0.x, p0.x), hv.x, s0);
            s1 = fmaf(fmaf(f, p1.y - p1.x, p1.x), hv.y, s1);
        }
    } else {
        for (int e = s; e < s + n; ++e) {
            const int2 m = pmeta[e];
            const float u = __int_as_float(m.y);
            int i0 = (int)u;
            i0 = (i0 > TBL - 2) ? (TBL - 2) : i0;
            const float f = u - (float)i0;
            const uint2 pr = *(const uint2*)(tabI + (size_t)i0 * H + col0);
            const __half2* ph = (const __half2*)&pr;
            const float2 p0 = __half22float2(ph[0]);
            const float2 p1 = __half22float2(ph[1]);
            const float2 hv = *(const float2*)(h + (size_t)m.x * H + col0);
            s0 = fmaf(fmaf(f, p0.y - p0.x, p0.x), hv.x, s0);
            s1 = fmaf(fmaf(f, p1.y - p1.x, p1.x), hv.y, s1);
        }
    }
    *(float2*)(agg + (size_t)a * H + col0) = make_float2(s0, s1);
}

// ---------------- K5: energy, 64 atoms x 64 cols per 256-thread block ----------------
__global__ __launch_bounds__(256) void k_out(const float* __restrict__ x,
                                             const float* __restrict__ o1w,
                                             const float* __restrict__ o1b,
                                             const float* __restrict__ o2w,
                                             const float* __restrict__ o2b,
                                             float* __restrict__ out) {
    __shared__ float xs[64 * 132];
    const int tid = threadIdx.x;
    const int abase = blockIdx.x * 64;

#pragma unroll
    for (int i = 0; i < 8; ++i) {
        int flat4 = tid + 256 * i;
        int r = flat4 >> 5, k4 = flat4 & 31;
        float4 v = ((const float4*)(x + (size_t)(abase + r) * H))[k4];
        float* dp = &xs[r * 132 + k4 * 4];
        dp[0] = v.x; dp[1] = v.y; dp[2] = v.z; dp[3] = v.w;
    }
    __syncthreads();

    const int eg = tid >> 4, cg = tid & 15;
    const int r0 = eg * 4, c0 = cg * 4;

    float acc[4][4];
#pragma unroll
    for (int i = 0; i < 4; ++i)
#pragma unroll
        for (int j = 0; j < 4; ++j) acc[i][j] = 0.0f;

#pragma unroll 4
    for (int k = 0; k < H; ++k) {
        float a[4];
#pragma unroll
        for (int i = 0; i < 4; ++i) a[i] = xs[(r0 + i) * 132 + k];
        const float4 b = *(const float4*)(o1w + (size_t)k * 64 + c0);
        const float bb[4] = {b.x, b.y, b.z, b.w};
#pragma unroll
        for (int i = 0; i < 4; ++i)
#pragma unroll
            for (int j = 0; j < 4; ++j) acc[i][j] = fmaf(a[i], bb[j], acc[i][j]);
    }

    const float4 ob = *(const float4*)(o1b + c0);
    const float4 ow = *(const float4*)(o2w + c0);
    const float obv[4] = {ob.x, ob.y, ob.z, ob.w};
    const float owv[4] = {ow.x, ow.y, ow.z, ow.w};
    float p[4];
#pragma unroll
    for (int i = 0; i < 4; ++i) {
        float s = 0.0f;
#pragma unroll
        for (int j = 0; j < 4; ++j) s = fmaf(fast_tanh(acc[i][j] + obv[j]), owv[j], s);
        p[i] = s;
    }
#pragma unroll
    for (int off = 1; off < 16; off <<= 1) {
#pragma unroll
        for (int i = 0; i < 4; ++i) p[i] += __shfl_xor(p[i], off, 64);
    }
    if (cg == 0) {
        const float b2 = o2b[0];
#pragma unroll
        for (int i = 0; i < 4; ++i) out[abase + r0 + i] = p[i] + b2;
    }
}

extern "C" void kernel_launch(void* const* d_in, const int* in_sizes, int n_in,
                              void* d_out, int out_size, void* d_ws, size_t ws_size,
                              hipStream_t stream) {
    const int*   types = (const int*)d_in[0];
    const int*   eidx  = (const int*)d_in[1];
    const float* ew    = (const float*)d_in[2];
    const float* emb   = (const float*)d_in[3];
    const float* lin1  = (const float*)d_in[4];
    const float* fw1   = (const float*)d_in[5];
    const float* fb1   = (const float*)d_in[6];
    const float* fw2   = (const float*)d_in[7];
    const float* fb2   = (const float*)d_in[8];
    const float* lin2  = (const float*)d_in[9];
    const float* lin2b = (const float*)d_in[10];
    const float* linw  = (const float*)d_in[11];
    const float* linb  = (const float*)d_in[12];
    const float* o1w   = (const float*)d_in[13];
    const float* o1b   = (const float*)d_in[14];
    const float* o2w   = (const float*)d_in[15];
    const float* o2b   = (const float*)d_in[16];
    float* out = (float*)d_out;

    // ws carve (tab as half2 = 4B per entry -> counts as one float each)
    float* x      = (float*)d_ws;                            // N*H
    float* h      = x + (size_t)N_ATOMS * H;                 // N*H
    float* agg    = h + (size_t)N_ATOMS * H;                 // N*H
    float* tab    = agg + (size_t)N_ATOMS * H;               // NBLK*TBL*H (half2 units)
    float* embw   = tab + (size_t)NBLK * TBL * H;            // 100*H
    int*   cnt    = (int*)(embw + 100 * H);                  // N
    int*   cursor = cnt + N_ATOMS;                           // N
    int*   rstart = cursor + N_ATOMS;                        // N
    int*   bsum   = rstart + N_ATOMS;                        // 40 (pad 64)
    int*   boff   = bsum + 64;                               // 40 (pad 64)
    int2*  pmeta  = (int2*)(boff + 64);                      // E

    // ---- CSR build ----
    hipMemsetAsync(cnt, 0, N_ATOMS * sizeof(int), stream);
    k_count<<<E_EDGES / 256, 256, 0, stream>>>(eidx, cnt);
    k_scanA<<<40, 1024, 0, stream>>>(cnt, bsum);
    k_scanB<<<1, 64, 0, stream>>>(bsum, boff);
    k_scanC<<<40, 1024, 0, stream>>>(cnt, boff, cursor, rstart);
    k_fill<<<E_EDGES / 256, 256, 0, stream>>>(eidx, ew, cursor, pmeta);
    // after k_fill, cursor[a] == row end of atom a

    // ---- type-table h0, embed, filter tables ----
    k_embw<<<100, 128, 0, stream>>>(emb, lin1, embw);
    k_embed2<<<(N_ATOMS * H / 4) / 256, 256, 0, stream>>>(types, emb, embw, x, h);
    k_table<<<dim3(TBL / 128, NBLK), 256, 0, stream>>>(fw1, fb1, fw2, fb2, (__half*)tab);

    for (int b = 0; b < NBLK; ++b) {
        k_edge5<<<N_ATOMS / 4, 256, 0, stream>>>(rstart, cursor, pmeta,
                                                 (const __half2*)tab + (size_t)b * TBL * H,
                                                 h, agg);
        if (b < NBLK - 1) {
            k_tail<true><<<N_ATOMS / 64, 256, 0, stream>>>(
                agg, lin2 + (size_t)b * H * H, lin2b + (size_t)b * H,
                linw + (size_t)b * H * H, linb + (size_t)b * H, x,
                lin1 + (size_t)(b + 1) * H * H, h);
        } else {
            k_tail<false><<<N_ATOMS / 64, 256, 0, stream>>>(
                agg, lin2 + (size_t)b * H * H, lin2b + (size_t)b * H,
                linw + (size_t)b * H * H, linb + (size_t)b * H, x,
                nullptr, nullptr);
        }
    }

    k_out<<<N_ATOMS / 64, 256, 0, stream>>>(x, o1w, o1b, o2w, o2b, out);
}

// Round 15
// 607.967 us; speedup vs baseline: 1.2247x; 1.0148x over previous
//
#include <hip/hip_runtime.h>
#include <hip/hip_fp16.h>
#include <math.h>

#define N_ATOMS 40000
#define E_EDGES 640000
#define H 128
#define RBF 64
#define NBLK 3
#define CUTF 5.0f
#define TBL 4096   // filter lookup table entries per block (1 MB fp16-pair -> L2-resident)

// stable fast tanh: exp-based, saturates correctly at +/-inf
__device__ __forceinline__ float fast_tanh(float x) {
    return 1.0f - 2.0f / (1.0f + __expf(2.0f * x));
}

// ---------------- embW = emb @ lin1[0]  (100 x 128) ----------------
__global__ __launch_bounds__(128) void k_embw(const float* __restrict__ emb,
                                              const float* __restrict__ lin1,
                                              float* __restrict__ embw) {
    const int t = blockIdx.x;
    const int c = threadIdx.x;
    float s = 0.0f;
#pragma unroll 8
    for (int k = 0; k < H; ++k) s = fmaf(emb[t * H + k], lin1[(size_t)k * H + c], s);
    embw[t * H + c] = s;
}

// ---------------- K0: x = emb[atom_types]; h = embW[atom_types] ----------------
__global__ __launch_bounds__(256) void k_embed2(const int* __restrict__ types,
                                                const float* __restrict__ emb,
                                                const float* __restrict__ embw,
                                                float* __restrict__ x,
                                                float* __restrict__ h) {
    int flat4 = blockIdx.x * 256 + threadIdx.x;  // over N*H/4
    int i = flat4 >> 5;
    int c4 = flat4 & 31;
    int t = types[i];
    ((float4*)(x + (size_t)i * H))[c4] = ((const float4*)(emb + (size_t)t * H))[c4];
    ((float4*)(h + (size_t)i * H))[c4] = ((const float4*)(embw + (size_t)t * H))[c4];
}

// ---------------- CSR build ----------------
__global__ __launch_bounds__(256) void k_count(const int* __restrict__ eidx,
                                               int* __restrict__ cnt) {
    int e = blockIdx.x * 256 + threadIdx.x;
    atomicAdd(&cnt[eidx[E_EDGES + e]], 1);
}

__global__ __launch_bounds__(1024) void k_scanA(const int* __restrict__ cnt,
                                                int* __restrict__ bsum) {
    __shared__ int ws[16];
    const int tid = threadIdx.x, lane = tid & 63, wid = tid >> 6;
    int idx = blockIdx.x * 1024 + tid;
    int v = (idx < N_ATOMS) ? cnt[idx] : 0;
#pragma unroll
    for (int off = 32; off; off >>= 1) v += __shfl_xor(v, off, 64);
    if (lane == 0) ws[wid] = v;
    __syncthreads();
    if (tid == 0) {
        int s = 0;
#pragma unroll
        for (int w = 0; w < 16; ++w) s += ws[w];
        bsum[blockIdx.x] = s;
    }
}

__global__ __launch_bounds__(64) void k_scanB(const int* __restrict__ bsum,
                                              int* __restrict__ boff) {
    const int lane = threadIdx.x;
    int v = (lane < 40) ? bsum[lane] : 0;
    int inc = v;
#pragma unroll
    for (int off = 1; off < 64; off <<= 1) {
        int t = __shfl_up(inc, off, 64);
        if (lane >= off) inc += t;
    }
    if (lane < 40) boff[lane] = inc - v;
}

__global__ __launch_bounds__(1024) void k_scanC(const int* __restrict__ cnt,
                                                const int* __restrict__ boff,
                                                int* __restrict__ cursor,
                                                int* __restrict__ rstart) {
    __shared__ int wsum[16];
    __shared__ int woff[16];
    const int tid = threadIdx.x, lane = tid & 63, wid = tid >> 6;
    int idx = blockIdx.x * 1024 + tid;
    int v = (idx < N_ATOMS) ? cnt[idx] : 0;
    int inc = v;
#pragma unroll
    for (int off = 1; off < 64; off <<= 1) {
        int t = __shfl_up(inc, off, 64);
        if (lane >= off) inc += t;
    }
    if (lane == 63) wsum[wid] = inc;
    __syncthreads();
    if (tid == 0) {
        int acc = 0;
#pragma unroll
        for (int w = 0; w < 16; ++w) { woff[w] = acc; acc += wsum[w]; }
    }
    __syncthreads();
    if (idx < N_ATOMS) {
        int ex = boff[blockIdx.x] + woff[wid] + inc - v;
        cursor[idx] = ex;
        rstart[idx] = ex;
    }
}

// fill: pmeta[pos] = {src, float_bits(u)}, u = d*(TBL-1)/CUT (dst-sorted)
__global__ __launch_bounds__(256) void k_fill(const int* __restrict__ eidx,
                                              const float* __restrict__ ew,
                                              int* __restrict__ cursor,
                                              int2* __restrict__ pmeta) {
    int e = blockIdx.x * 256 + threadIdx.x;
    int dd = eidx[E_EDGES + e];
    int pos = atomicAdd(&cursor[dd], 1);
    float u = ew[e] * ((float)(TBL - 1) / CUTF);
    pmeta[pos] = make_int2(eidx[e], __float_as_int(u));
}

// ---------------- K1: filter table build (fp16 interleaved pairs) ----------------
// tabI[m][c] = half2{ W(m)[c]*C(m), W(m+1)[c]*C(m+1) } so one row read gives both
// lerp endpoints. Entry m's .x written by row m, entry m-1's .y by row m.
__global__ __launch_bounds__(256, 2) void k_table(const float* __restrict__ fw1all,
                                                  const float* __restrict__ fb1all,
                                                  const float* __restrict__ fw2all,
                                                  const float* __restrict__ fb2all,
                                                  __half* __restrict__ tabH_all) {
    const int b = blockIdx.y;
    const float* fw1 = fw1all + (size_t)b * RBF * H;
    const float* fb1 = fb1all + (size_t)b * H;
    const float* fw2 = fw2all + (size_t)b * H * H;
    const float* fb2 = fb2all + (size_t)b * H;
    __half* tabH = tabH_all + (size_t)b * TBL * H * 2;

    __shared__ float tile[128 * 133];
    const int tid = threadIdx.x;
    const int mbase = blockIdx.x * 128;
    const float DSTEP = CUTF / (float)(TBL - 1);

    {
        const int e = tid & 127;
        const int k0 = (tid >> 7) * 32;
        const float d = (float)(mbase + e) * DSTEP;
        const float DELTA = CUTF / 63.0f;
        const float COEFF = -0.5f / (DELTA * DELTA);
#pragma unroll
        for (int k = k0; k < k0 + 32; ++k) {
            float diff = d - (float)k * DELTA;
            tile[e * 133 + k] = __expf(COEFF * diff * diff);
        }
    }
    __syncthreads();

    const int eg = tid >> 4, cg = tid & 15;
    const int e0 = eg * 8, c0 = cg * 8;

    float acc[8][8];
#pragma unroll
    for (int i = 0; i < 8; ++i)
#pragma unroll
        for (int j = 0; j < 8; ++j) acc[i][j] = 0.0f;

#pragma unroll 4
    for (int k = 0; k < RBF; ++k) {
        float a[8];
#pragma unroll
        for (int i = 0; i < 8; ++i) a[i] = tile[(e0 + i) * 133 + k];
        const float4 b0 = *(const float4*)(fw1 + (size_t)k * H + c0);
        const float4 b1 = *(const float4*)(fw1 + (size_t)k * H + c0 + 4);
        const float bb[8] = {b0.x, b0.y, b0.z, b0.w, b1.x, b1.y, b1.z, b1.w};
#pragma unroll
        for (int i = 0; i < 8; ++i)
#pragma unroll
            for (int j = 0; j < 8; ++j) acc[i][j] = fmaf(a[i], bb[j], acc[i][j]);
    }

    {
        const float4 q0 = *(const float4*)(fb1 + c0);
        const float4 q1 = *(const float4*)(fb1 + c0 + 4);
        const float bv[8] = {q0.x, q0.y, q0.z, q0.w, q1.x, q1.y, q1.z, q1.w};
#pragma unroll
        for (int i = 0; i < 8; ++i)
#pragma unroll
            for (int j = 0; j < 8; ++j) acc[i][j] = fast_tanh(acc[i][j] + bv[j]);
    }

    __syncthreads();
#pragma unroll
    for (int i = 0; i < 8; ++i)
#pragma unroll
        for (int j = 0; j < 8; ++j) tile[(e0 + i) * 133 + c0 + j] = acc[i][j];
    __syncthreads();

#pragma unroll
    for (int i = 0; i < 8; ++i)
#pragma unroll
        for (int j = 0; j < 8; ++j) acc[i][j] = 0.0f;

#pragma unroll 4
    for (int k = 0; k < H; ++k) {
        float a[8];
#pragma unroll
        for (int i = 0; i < 8; ++i) a[i] = tile[(e0 + i) * 133 + k];
        const float4 b0 = *(const float4*)(fw2 + (size_t)k * H + c0);
        const float4 b1 = *(const float4*)(fw2 + (size_t)k * H + c0 + 4);
        const float bb[8] = {b0.x, b0.y, b0.z, b0.w, b1.x, b1.y, b1.z, b1.w};
#pragma unroll
        for (int i = 0; i < 8; ++i)
#pragma unroll
            for (int j = 0; j < 8; ++j) acc[i][j] = fmaf(a[i], bb[j], acc[i][j]);
    }

    const float4 q0 = *(const float4*)(fb2 + c0);
    const float4 q1 = *(const float4*)(fb2 + c0 + 4);
    const float bv[8] = {q0.x, q0.y, q0.z, q0.w, q1.x, q1.y, q1.z, q1.w};

#pragma unroll
    for (int ei = 0; ei < 8; ++ei) {
        const int m = mbase + e0 + ei;
        const float d = (float)m * DSTEP;
        float c = 0.5f * (cosf(0.6283185307179586f * d) + 1.0f);
        c = (d < CUTF) ? c : 0.0f;
#pragma unroll
        for (int j = 0; j < 8; ++j) {
            const int col = c0 + j;
            const __half hv = __float2half_rn((acc[ei][j] + bv[j]) * c);
            tabH[((size_t)m * H + col) * 2] = hv;                      // entry m, .x
            if (m > 0)
                tabH[((size_t)(m - 1) * H + col) * 2 + 1] = hv;        // entry m-1, .y
        }
    }
}

// ---------------- LDS-staged weight panels for the tail GEMMs ----------------
// Panel = 16 rows x 128 cols of W (8 KB), loaded by global_load_lds width-16.
__device__ __forceinline__ void stage_panel(const float* __restrict__ Wg,
                                            float* wbuf, int tid) {
    const int w = tid >> 6, lane = tid & 63;
#pragma unroll
    for (int i = 0; i < 2; ++i) {
        const float* g = Wg + ((w * 2 + i) * 256) + (lane << 2);
        float* l = wbuf + (w * 2 + i) * 256;   // uniform across the wave
        __builtin_amdgcn_global_load_lds((const __attribute__((address_space(1))) void*)g,
                                         (__attribute__((address_space(3))) void*)l,
                                         16, 0, 0);
    }
}

// acc += A(64x128 LDS, stride 132) @ W(128x128 global via 8x 16-row LDS panels).
// Split-column map: thread covers cols [cA,cA+4) and [cB,cB+4) (cB = cA+64)
// -> W ds_read_b128 is 256B/16-lane contiguous = 2-way bank alias = free.
// p-loop unrolled by 2 (NOT fully): keeps cur/nxt parity static for the
// double-buffer while holding compile-time code size down (R12/R13 full-unroll
// builds never came back from the container -- compile blowup).
__device__ __forceinline__ void gemm_lds(const float* __restrict__ at,
                                         const float* __restrict__ Wg,
                                         float* __restrict__ wb0,
                                         float* __restrict__ wb1,
                                         int tid, int r0, int cA, int cB,
                                         float acc[4][8]) {
#pragma unroll
    for (int i = 0; i < 4; ++i)
#pragma unroll
        for (int j = 0; j < 8; ++j) acc[i][j] = 0.0f;

    stage_panel(Wg, wb0, tid);
    __syncthreads();   // panel 0 resident (also covers at[] staging before 1st call)

#pragma unroll 2
    for (int p = 0; p < 8; ++p) {
        float* cur = (p & 1) ? wb1 : wb0;
        float* nxt = (p & 1) ? wb0 : wb1;
        if (p < 7) stage_panel(Wg + (size_t)(p + 1) * 16 * H, nxt, tid);
        const int kb = p * 16;
#pragma unroll
        for (int k4 = 0; k4 < 16; k4 += 4) {
            float4 av[4];
#pragma unroll
            for (int i = 0; i < 4; ++i)
                av[i] = *(const float4*)&at[(r0 + i) * 132 + kb + k4];
            const float* avf = (const float*)av;
#pragma unroll
            for (int kk = 0; kk < 4; ++kk) {
                const float4 w0 = *(const float4*)&cur[(k4 + kk) * H + cA];
                const float4 w1 = *(const float4*)&cur[(k4 + kk) * H + cB];
                const float wv[8] = {w0.x, w0.y, w0.z, w0.w, w1.x, w1.y, w1.z, w1.w};
#pragma unroll
                for (int i = 0; i < 4; ++i) {
                    const float a = avf[i * 4 + kk];
#pragma unroll
                    for (int j = 0; j < 8; ++j) acc[i][j] = fmaf(a, wv[j], acc[i][j]);
                }
            }
        }
        __syncthreads();   // all reads of cur done; next panel's loads landed
    }
}

// ---------------- fused tail (256 thr, 64-atom tile, split-col 4x8 micro):
// x += tanh(agg@lin2+b2)@linw + bl ; optionally h = x_new@lin1_next
template <bool MAKE_H>
__global__ __launch_bounds__(256) void k_tail(const float* __restrict__ agg,
                                              const float* __restrict__ lin2,
                                              const float* __restrict__ b2,
                                              const float* __restrict__ linw,
                                              const float* __restrict__ bl,
                                              float* __restrict__ x,
                                              const float* __restrict__ lin1n,
                                              float* __restrict__ hout) {
    __shared__ float at[64 * 132];
    __shared__ float wpan0[16 * H];
    __shared__ float wpan1[16 * H];
    const int tid = threadIdx.x;
    const int abase = blockIdx.x * 64;

    // stage agg tile [64][128] -> LDS (stride 132)
#pragma unroll
    for (int i = 0; i < 8; ++i) {
        int flat4 = tid + 256 * i;
        int r = flat4 >> 5, k4 = flat4 & 31;
        float4 v = ((const float4*)(agg + (size_t)(abase + r) * H))[k4];
        *(float4*)&at[r * 132 + k4 * 4] = v;
    }
    // gemm_lds prologue barrier covers visibility

    const int eg = tid >> 4, cg = tid & 15;   // 16 x 16 thread grid
    const int r0 = eg * 4;
    const int cA = cg * 4, cB = 64 + cg * 4;  // split column groups

    float acc[4][8];

    // stage 1: tanh(agg @ lin2 + b2)
    gemm_lds(at, lin2, wpan0, wpan1, tid, r0, cA, cB, acc);
    {
        const float4 q0 = *(const float4*)(b2 + cA);
        const float4 q1 = *(const float4*)(b2 + cB);
        const float bv[8] = {q0.x, q0.y, q0.z, q0.w, q1.x, q1.y, q1.z, q1.w};
#pragma unroll
        for (int i = 0; i < 4; ++i)
#pragma unroll
            for (int j = 0; j < 8; ++j) acc[i][j] = fast_tanh(acc[i][j] + bv[j]);
    }
    // write t tile (float4 per col-group; 2-way alias = free)
#pragma unroll
    for (int i = 0; i < 4; ++i) {
        *(float4*)&at[(r0 + i) * 132 + cA] = make_float4(acc[i][0], acc[i][1], acc[i][2], acc[i][3]);
        *(float4*)&at[(r0 + i) * 132 + cB] = make_float4(acc[i][4], acc[i][5], acc[i][6], acc[i][7]);
    }
    __syncthreads();

    // stage 2: t @ linw ; x += . + bl
    gemm_lds(at, linw, wpan0, wpan1, tid, r0, cA, cB, acc);
    {
        const float4 q0 = *(const float4*)(bl + cA);
        const float4 q1 = *(const float4*)(bl + cB);
        const float bv[8] = {q0.x, q0.y, q0.z, q0.w, q1.x, q1.y, q1.z, q1.w};
#pragma unroll
        for (int ei = 0; ei < 4; ++ei) {
            const int row = abase + r0 + ei;
            float* opA = x + (size_t)row * H + cA;
            float* opB = x + (size_t)row * H + cB;
            float4 x0 = *(const float4*)(opA);
            float4 x1 = *(const float4*)(opB);
            float xn[8] = {x0.x + acc[ei][0] + bv[0], x0.y + acc[ei][1] + bv[1],
                           x0.z + acc[ei][2] + bv[2], x0.w + acc[ei][3] + bv[3],
                           x1.x + acc[ei][4] + bv[4], x1.y + acc[ei][5] + bv[5],
                           x1.z + acc[ei][6] + bv[6], x1.w + acc[ei][7] + bv[7]};
            *(float4*)(opA) = make_float4(xn[0], xn[1], xn[2], xn[3]);
            *(float4*)(opB) = make_float4(xn[4], xn[5], xn[6], xn[7]);
            if (MAKE_H) {
                *(float4*)&at[(r0 + ei) * 132 + cA] = make_float4(xn[0], xn[1], xn[2], xn[3]);
                *(float4*)&at[(r0 + ei) * 132 + cB] = make_float4(xn[4], xn[5], xn[6], xn[7]);
            }
        }
    }

    if (MAKE_H) {
        __syncthreads();
        // stage 3: h = x_new @ lin1_next
        gemm_lds(at, lin1n, wpan0, wpan1, tid, r0, cA, cB, acc);
#pragma unroll
        for (int ei = 0; ei < 4; ++ei) {
            const int row = abase + r0 + ei;
            *(float4*)(hout + (size_t)row * H + cA) =
                make_float4(acc[ei][0], acc[ei][1], acc[ei][2], acc[ei][3]);
            *(float4*)(hout + (size_t)row * H + cB) =
                make_float4(acc[ei][4], acc[ei][5], acc[ei][6], acc[ei][7]);
        }
    }
}

// ---------------- K2: atom-centric gather, fp16 pair-table, batched loads ----------------
// Per 8-edge chunk: hoist all 16 tab/h loads before any FMA (MLP 8x vs the
// former serial per-edge chain). Chunk-validity predicate (e < m) is
// wave-uniform, so no divergence; invalid slots contribute exact zeros.
__global__ __launch_bounds__(256) void k_edge6(const int* __restrict__ rstart,
                                               const int* __restrict__ rend,
                                               const int2* __restrict__ pmeta,
                                               const __half2* __restrict__ tabI,
                                               const float* __restrict__ h,
                                               float* __restrict__ agg) {
    const int wave = threadIdx.x >> 6;
    const int lane = threadIdx.x & 63;
    const int a = blockIdx.x * 4 + wave;
    const int col0 = lane * 2;

    const int s = rstart[a];
    const int n = rend[a] - s;

    float s0 = 0.0f, s1 = 0.0f;

    for (int w0 = 0; w0 < n; w0 += 64) {
        int2 meta = make_int2(0, 0);
        if (w0 + lane < n) meta = pmeta[s + w0 + lane];
        const int m = (n - w0 < 64) ? (n - w0) : 64;

        for (int base = 0; base < m; base += 8) {
            uint2 pr[8];
            float2 hv[8];
            float f[8];
#pragma unroll
            for (int c = 0; c < 8; ++c) {
                const int e = base + c;
                const int src = __shfl(meta.x, e, 64);
                const float u = __int_as_float(__shfl(meta.y, e, 64));
                int i0 = (int)u;
                i0 = (i0 > TBL - 2) ? (TBL - 2) : i0;
                f[c] = u - (float)i0;
                if (e < m) {   // wave-uniform predicate
                    pr[c] = *(const uint2*)(tabI + (size_t)i0 * H + col0);
                    hv[c] = *(const float2*)(h + (size_t)src * H + col0);
                } else {
                    pr[c] = make_uint2(0u, 0u);
                    hv[c] = make_float2(0.0f, 0.0f);
                    f[c] = 0.0f;
                }
            }
#pragma unroll
            for (int c = 0; c < 8; ++c) {
                const __half2* ph = (const __half2*)&pr[c];
                const float2 p0 = __half22float2(ph[0]);
                const float2 p1 = __half22float2(ph[1]);
                s0 = fmaf(fmaf(f[c], p0.y - p0.x, p0.x), hv[c].x, s0);
                s1 = fmaf(fmaf(f[c], p1.y - p1.x, p1.x), hv[c].y, s1);
            }
        }
    }
    *(float2*)(agg + (size_t)a * H + col0) = make_float2(s0, s1);
}

// ---------------- K5: energy, 64 atoms x 64 cols per 256-thread block ----------------
__global__ __launch_bounds__(256) void k_out(const float* __restrict__ x,
                                             const float* __restrict__ o1w,
                                             const float* __restrict__ o1b,
                                             const float* __restrict__ o2w,
                                             const float* __restrict__ o2b,
                                             float* __restrict__ out) {
    __shared__ float xs[64 * 132];
    const int tid = threadIdx.x;
    const int abase = blockIdx.x * 64;

#pragma unroll
    for (int i = 0; i < 8; ++i) {
        int flat4 = tid + 256 * i;
        int r = flat4 >> 5, k4 = flat4 & 31;
        float4 v = ((const float4*)(x + (size_t)(abase + r) * H))[k4];
        float* dp = &xs[r * 132 + k4 * 4];
        dp[0] = v.x; dp[1] = v.y; dp[2] = v.z; dp[3] = v.w;
    }
    __syncthreads();

    const int eg = tid >> 4, cg = tid & 15;
    const int r0 = eg * 4, c0 = cg * 4;

    float acc[4][4];
#pragma unroll
    for (int i = 0; i < 4; ++i)
#pragma unroll
        for (int j = 0; j < 4; ++j) acc[i][j] = 0.0f;

#pragma unroll 4
    for (int k = 0; k < H; ++k) {
        float a[4];
#pragma unroll
        for (int i = 0; i < 4; ++i) a[i] = xs[(r0 + i) * 132 + k];
        const float4 b = *(const float4*)(o1w + (size_t)k * 64 + c0);
        const float bb[4] = {b.x, b.y, b.z, b.w};
#pragma unroll
        for (int i = 0; i < 4; ++i)
#pragma unroll
            for (int j = 0; j < 4; ++j) acc[i][j] = fmaf(a[i], bb[j], acc[i][j]);
    }

    const float4 ob = *(const float4*)(o1b + c0);
    const float4 ow = *(const float4*)(o2w + c0);
    const float obv[4] = {ob.x, ob.y, ob.z, ob.w};
    const float owv[4] = {ow.x, ow.y, ow.z, ow.w};
    float p[4];
#pragma unroll
    for (int i = 0; i < 4; ++i) {
        float s = 0.0f;
#pragma unroll
        for (int j = 0; j < 4; ++j) s = fmaf(fast_tanh(acc[i][j] + obv[j]), owv[j], s);
        p[i] = s;
    }
#pragma unroll
    for (int off = 1; off < 16; off <<= 1) {
#pragma unroll
        for (int i = 0; i < 4; ++i) p[i] += __shfl_xor(p[i], off, 64);
    }
    if (cg == 0) {
        const float b2 = o2b[0];
#pragma unroll
        for (int i = 0; i < 4; ++i) out[abase + r0 + i] = p[i] + b2;
    }
}

extern "C" void kernel_launch(void* const* d_in, const int* in_sizes, int n_in,
                              void* d_out, int out_size, void* d_ws, size_t ws_size,
                              hipStream_t stream) {
    const int*   types = (const int*)d_in[0];
    const int*   eidx  = (const int*)d_in[1];
    const float* ew    = (const float*)d_in[2];
    const float* emb   = (const float*)d_in[3];
    const float* lin1  = (const float*)d_in[4];
    const float* fw1   = (const float*)d_in[5];
    const float* fb1   = (const float*)d_in[6];
    const float* fw2   = (const float*)d_in[7];
    const float* fb2   = (const float*)d_in[8];
    const float* lin2  = (const float*)d_in[9];
    const float* lin2b = (const float*)d_in[10];
    const float* linw  = (const float*)d_in[11];
    const float* linb  = (const float*)d_in[12];
    const float* o1w   = (const float*)d_in[13];
    const float* o1b   = (const float*)d_in[14];
    const float* o2w   = (const float*)d_in[15];
    const float* o2b   = (const float*)d_in[16];
    float* out = (float*)d_out;

    // ws carve (tab as half2 = 4B per entry -> counts as one float each)
    float* x      = (float*)d_ws;                            // N*H
    float* h      = x + (size_t)N_ATOMS * H;                 // N*H
    float* agg    = h + (size_t)N_ATOMS * H;                 // N*H
    float* tab    = agg + (size_t)N_ATOMS * H;               // NBLK*TBL*H (half2 units)
    float* embw   = tab + (size_t)NBLK * TBL * H;            // 100*H
    int*   cnt    = (int*)(embw + 100 * H);                  // N
    int*   cursor = cnt + N_ATOMS;                           // N
    int*   rstart = cursor + N_ATOMS;                        // N
    int*   bsum   = rstart + N_ATOMS;                        // 40 (pad 64)
    int*   boff   = bsum + 64;                               // 40 (pad 64)
    int2*  pmeta  = (int2*)(boff + 64);                      // E

    // ---- CSR build ----
    hipMemsetAsync(cnt, 0, N_ATOMS * sizeof(int), stream);
    k_count<<<E_EDGES / 256, 256, 0, stream>>>(eidx, cnt);
    k_scanA<<<40, 1024, 0, stream>>>(cnt, bsum);
    k_scanB<<<1, 64, 0, stream>>>(bsum, boff);
    k_scanC<<<40, 1024, 0, stream>>>(cnt, boff, cursor, rstart);
    k_fill<<<E_EDGES / 256, 256, 0, stream>>>(eidx, ew, cursor, pmeta);
    // after k_fill, cursor[a] == row end of atom a

    // ---- type-table h0, embed, filter tables ----
    k_embw<<<100, 128, 0, stream>>>(emb, lin1, embw);
    k_embed2<<<(N_ATOMS * H / 4) / 256, 256, 0, stream>>>(types, emb, embw, x, h);
    k_table<<<dim3(TBL / 128, NBLK), 256, 0, stream>>>(fw1, fb1, fw2, fb2, (__half*)tab);

    for (int b = 0; b < NBLK; ++b) {
        k_edge6<<<N_ATOMS / 4, 256, 0, stream>>>(rstart, cursor, pmeta,
                                                 (const __half2*)tab + (size_t)b * TBL * H,
                                                 h, agg);
        if (b < NBLK - 1) {
            k_tail<true><<<N_ATOMS / 64, 256, 0, stream>>>(
                agg, lin2 + (size_t)b * H * H, lin2b + (size_t)b * H,
                linw + (size_t)b * H * H, linb + (size_t)b * H, x,
                lin1 + (size_t)(b + 1) * H * H, h);
        } else {
            k_tail<false><<<N_ATOMS / 64, 256, 0, stream>>>(
                agg, lin2 + (size_t)b * H * H, lin2b + (size_t)b * H,
                linw + (size_t)b * H * H, linb + (size_t)b * H, x,
                nullptr, nullptr);
        }
    }

    k_out<<<N_ATOMS / 64, 256, 0, stream>>>(x, o1w, o1b, o2w, o2b, out);
}